// Round 1
// baseline (157.091 us; speedup 1.0000x reference)
//
#include <hip/hip_runtime.h>

// Problem: B=2048, D=512, all fp32.
// q = query@Wq.T+bq ; k,v likewise. attn[b,i,j]=q_i*k_j (rank-1!),
// softmax over j, out[b,i] = sum_j softmax_j(q_i*k_j)*v_j.
//
// Round 5:
//  - split_prepass: one-time fp32 -> (hi,lo) bf16 truncation split of X and W
//    (Wk and bk get pre-scaled by log2(e) so the k-projection lands in log2
//    domain for free). Removes all split VALU from the GEMM K-loop and the
//    x8/x32 redundant re-splitting across tiles.
//  - qkv_gemm_mfma: identical proven tile/frag/epilogue structure, staging
//    now loads pre-split bf16 directly (coalesced 8B loads -> ds_write).
//  - attn_kernel: inner loop packed ACROSS j with forced v_pk_fma_f32 /
//    v_pk_add_f32 inline asm ({q,q},{c,c} broadcast pairs hoisted). 3 VALU +
//    2 trans per j instead of ~6 + 2; trans pipe (v_exp_f32) becomes the
//    floor (~27 us chip-wide).

#define B_SZ 2048
#define D_SZ 512
#define LOG2E 1.44269504088896340736f

typedef __attribute__((ext_vector_type(2))) float  f32x2;
typedef __attribute__((ext_vector_type(4))) float  f32x4;
typedef __attribute__((ext_vector_type(8))) short  bf16x8;   // MFMA A/B carrier
typedef __attribute__((ext_vector_type(4))) unsigned short u16x4;
typedef __attribute__((ext_vector_type(8))) unsigned short u16x8;

__device__ __forceinline__ float exp2_raw(float x) {
#if defined(__has_builtin) && __has_builtin(__builtin_amdgcn_exp2f)
    return __builtin_amdgcn_exp2f(x);
#else
    return exp2f(x);
#endif
}

// Forced packed fp32 math (compiler was emitting scalar for f32x2 exprs).
__device__ __forceinline__ f32x2 pk_fma(f32x2 a, f32x2 b, f32x2 c) {
    f32x2 d;
    asm("v_pk_fma_f32 %0, %1, %2, %3" : "=v"(d) : "v"(a), "v"(b), "v"(c));
    return d;
}
__device__ __forceinline__ f32x2 pk_add(f32x2 a, f32x2 b) {
    f32x2 d;
    asm("v_pk_add_f32 %0, %1, %2" : "=v"(d) : "v"(a), "v"(b));
    return d;
}

// Truncation split: hi = top 16 bits of fp32; lo = bf16(trunc) of residual.
// |x - hi - lo| <= 2^-14 |x|
__device__ __forceinline__ void split1(float x, unsigned short& hi, unsigned short& lo) {
    unsigned int u = __float_as_uint(x);
    hi = (unsigned short)(u >> 16);
    float r = x - __uint_as_float(u & 0xFFFF0000u);
    lo = (unsigned short)(__float_as_uint(r) >> 16);
}

__device__ __forceinline__ void split4(const float4& x, u16x4& h, u16x4& l) {
    unsigned short hh, ll;
    split1(x.x, hh, ll); h.x = hh; l.x = ll;
    split1(x.y, hh, ll); h.y = hh; l.y = ll;
    split1(x.z, hh, ll); h.z = hh; l.z = ll;
    split1(x.w, hh, ll); h.w = hh; l.w = ll;
}

// ---------------------------------------------------------------------------
// Kernel 0: one-time hi/lo split of X (query,key,value) and W (Wq,Wk,Wv).
// z = 0..2 -> X inputs (2048x512), z = 3..5 -> W (512x512). z==4 (Wk) is
// pre-scaled by log2(e) so the GEMM emits k already in log2 domain.
// Thread handles 8 consecutive floats: fully coalesced both sides.
// ---------------------------------------------------------------------------
__global__ __launch_bounds__(256) void split_prepass(
    const float* __restrict__ Xq, const float* __restrict__ Xk, const float* __restrict__ Xv,
    const float* __restrict__ Wq, const float* __restrict__ Wk, const float* __restrict__ Wv,
    unsigned short* __restrict__ xhi, unsigned short* __restrict__ xlo,
    unsigned short* __restrict__ whi, unsigned short* __restrict__ wlo)
{
    const int z = blockIdx.z;
    const bool isW = (z >= 3);
    if (isW && blockIdx.x >= 128) return;   // W needs only 128 blocks

    const float* __restrict__ src =
        (z == 0) ? Xq : (z == 1) ? Xk : (z == 2) ? Xv :
        (z == 3) ? Wq : (z == 4) ? Wk : Wv;
    unsigned short* dh;
    unsigned short* dl;
    if (!isW) { size_t o = (size_t)z * B_SZ * D_SZ;       dh = xhi + o; dl = xlo + o; }
    else      { size_t o = (size_t)(z - 3) * D_SZ * D_SZ; dh = whi + o; dl = wlo + o; }

    const size_t i = ((size_t)blockIdx.x * 256 + threadIdx.x) * 8;
    const float s = (z == 4) ? LOG2E : 1.0f;

    float4 a = *(const float4*)(src + i);
    float4 b = *(const float4*)(src + i + 4);
    a.x *= s; a.y *= s; a.z *= s; a.w *= s;
    b.x *= s; b.y *= s; b.z *= s; b.w *= s;

    u16x4 h0, l0, h1, l1;
    split4(a, h0, l0);
    split4(b, h1, l1);
    u16x8 hh = {h0.x, h0.y, h0.z, h0.w, h1.x, h1.y, h1.z, h1.w};
    u16x8 ll = {l0.x, l0.y, l0.z, l0.w, l1.x, l1.y, l1.z, l1.w};
    *(u16x8*)(dh + i) = hh;
    *(u16x8*)(dl + i) = ll;
}

// ---------------------------------------------------------------------------
// Kernel 1: Y = X @ W^T + bias via split-bf16 MFMA, staged from pre-split
// arrays. 64x64 tile per block, 256 thr = 4 waves in 2x2; each wave 2x2 frags
// of 16x16x32 MFMA, 3 terms (hi*hi + lo*hi + hi*lo) into one fp32 acc.
// LDS [64][40] shorts (pad 40: frag b128 reads are 2-way = free).
// K-loop now has ZERO split VALU: 8x 8B coalesced loads -> 8x ds_write.
// ---------------------------------------------------------------------------
__global__ __launch_bounds__(256) void qkv_gemm_mfma(
    const unsigned short* __restrict__ xhi, const unsigned short* __restrict__ xlo,
    const unsigned short* __restrict__ whi, const unsigned short* __restrict__ wlo,
    const float* __restrict__ bq, const float* __restrict__ bk, const float* __restrict__ bv,
    float* __restrict__ qkv_out)
{
    const int which = blockIdx.z;
    const unsigned short* __restrict__ Ah = xhi + (size_t)which * B_SZ * D_SZ;
    const unsigned short* __restrict__ Al = xlo + (size_t)which * B_SZ * D_SZ;
    const unsigned short* __restrict__ Bh = whi + (size_t)which * D_SZ * D_SZ;
    const unsigned short* __restrict__ Bl = wlo + (size_t)which * D_SZ * D_SZ;
    const float* __restrict__ bias = (which == 0) ? bq : (which == 1) ? bk : bv;
    // which==1 (k): W was pre-scaled by log2e, so bias must be too.
    const float bscale = (which == 1) ? LOG2E : 1.0f;
    float* __restrict__ Y = qkv_out + (size_t)which * B_SZ * D_SZ;

    const int t    = threadIdx.x;
    const int lane = t & 63;
    const int wv   = t >> 6;
    const int l15  = lane & 15;
    const int quad = lane >> 4;
    const int wm   = (wv >> 1) * 32;
    const int wn   = (wv & 1) * 32;
    const int m0   = blockIdx.x * 64;
    const int n0   = blockIdx.y * 64;

    __shared__ unsigned short Ahi[64][40], Alo[64][40];
    __shared__ unsigned short Bhi[64][40], Blo[64][40];

    f32x4 acc[2][2] = {{{0.f,0.f,0.f,0.f},{0.f,0.f,0.f,0.f}},
                       {{0.f,0.f,0.f,0.f},{0.f,0.f,0.f,0.f}}};

    // staging: 64 rows x 8 u16x4-cols per array; 2 rows/thread
    const int r0 = t >> 3;            // 0..31
    const int c0 = (t & 7) * 4;       // 0,4,...,28 (shorts within 32-k chunk)
    const int r1 = r0 + 32;

    const unsigned short* pAh0 = Ah + (size_t)(m0 + r0) * D_SZ + c0;
    const unsigned short* pAh1 = Ah + (size_t)(m0 + r1) * D_SZ + c0;
    const unsigned short* pAl0 = Al + (size_t)(m0 + r0) * D_SZ + c0;
    const unsigned short* pAl1 = Al + (size_t)(m0 + r1) * D_SZ + c0;
    const unsigned short* pBh0 = Bh + (size_t)(n0 + r0) * D_SZ + c0;
    const unsigned short* pBh1 = Bh + (size_t)(n0 + r1) * D_SZ + c0;
    const unsigned short* pBl0 = Bl + (size_t)(n0 + r0) * D_SZ + c0;
    const unsigned short* pBl1 = Bl + (size_t)(n0 + r1) * D_SZ + c0;

    u16x4 va0h = *(const u16x4*)pAh0;
    u16x4 va1h = *(const u16x4*)pAh1;
    u16x4 va0l = *(const u16x4*)pAl0;
    u16x4 va1l = *(const u16x4*)pAl1;
    u16x4 vb0h = *(const u16x4*)pBh0;
    u16x4 vb1h = *(const u16x4*)pBh1;
    u16x4 vb0l = *(const u16x4*)pBl0;
    u16x4 vb1l = *(const u16x4*)pBl1;

    for (int kk = 0; kk < D_SZ; kk += 32) {
        __syncthreads();   // previous chunk's LDS fully consumed

        *(u16x4*)&Ahi[r0][c0] = va0h; *(u16x4*)&Ahi[r1][c0] = va1h;
        *(u16x4*)&Alo[r0][c0] = va0l; *(u16x4*)&Alo[r1][c0] = va1l;
        *(u16x4*)&Bhi[r0][c0] = vb0h; *(u16x4*)&Bhi[r1][c0] = vb1h;
        *(u16x4*)&Blo[r0][c0] = vb0l; *(u16x4*)&Blo[r1][c0] = vb1l;

        __syncthreads();

        // prefetch next chunk (MFMA below hides the latency)
        if (kk + 32 < D_SZ) {
            va0h = *(const u16x4*)(pAh0 + kk + 32);
            va1h = *(const u16x4*)(pAh1 + kk + 32);
            va0l = *(const u16x4*)(pAl0 + kk + 32);
            va1l = *(const u16x4*)(pAl1 + kk + 32);
            vb0h = *(const u16x4*)(pBh0 + kk + 32);
            vb1h = *(const u16x4*)(pBh1 + kk + 32);
            vb0l = *(const u16x4*)(pBl0 + kk + 32);
            vb1l = *(const u16x4*)(pBl1 + kk + 32);
        }

        // fragment loads: A[m=lane&15][k=quad*8+j] (m89/m120-verified layout)
        bf16x8 ah0 = *(const bf16x8*)&Ahi[wm + l15     ][quad * 8];
        bf16x8 ah1 = *(const bf16x8*)&Ahi[wm + 16 + l15][quad * 8];
        bf16x8 al0 = *(const bf16x8*)&Alo[wm + l15     ][quad * 8];
        bf16x8 al1 = *(const bf16x8*)&Alo[wm + 16 + l15][quad * 8];
        bf16x8 bh0 = *(const bf16x8*)&Bhi[wn + l15     ][quad * 8];
        bf16x8 bh1 = *(const bf16x8*)&Bhi[wn + 16 + l15][quad * 8];
        bf16x8 bl0 = *(const bf16x8*)&Blo[wn + l15     ][quad * 8];
        bf16x8 bl1 = *(const bf16x8*)&Blo[wn + 16 + l15][quad * 8];

        acc[0][0] = __builtin_amdgcn_mfma_f32_16x16x32_bf16(ah0, bh0, acc[0][0], 0, 0, 0);
        acc[0][0] = __builtin_amdgcn_mfma_f32_16x16x32_bf16(al0, bh0, acc[0][0], 0, 0, 0);
        acc[0][0] = __builtin_amdgcn_mfma_f32_16x16x32_bf16(ah0, bl0, acc[0][0], 0, 0, 0);
        acc[0][1] = __builtin_amdgcn_mfma_f32_16x16x32_bf16(ah0, bh1, acc[0][1], 0, 0, 0);
        acc[0][1] = __builtin_amdgcn_mfma_f32_16x16x32_bf16(al0, bh1, acc[0][1], 0, 0, 0);
        acc[0][1] = __builtin_amdgcn_mfma_f32_16x16x32_bf16(ah0, bl1, acc[0][1], 0, 0, 0);
        acc[1][0] = __builtin_amdgcn_mfma_f32_16x16x32_bf16(ah1, bh0, acc[1][0], 0, 0, 0);
        acc[1][0] = __builtin_amdgcn_mfma_f32_16x16x32_bf16(al1, bh0, acc[1][0], 0, 0, 0);
        acc[1][0] = __builtin_amdgcn_mfma_f32_16x16x32_bf16(ah1, bl0, acc[1][0], 0, 0, 0);
        acc[1][1] = __builtin_amdgcn_mfma_f32_16x16x32_bf16(ah1, bh1, acc[1][1], 0, 0, 0);
        acc[1][1] = __builtin_amdgcn_mfma_f32_16x16x32_bf16(al1, bh1, acc[1][1], 0, 0, 0);
        acc[1][1] = __builtin_amdgcn_mfma_f32_16x16x32_bf16(ah1, bl1, acc[1][1], 0, 0, 0);
    }

    // epilogue: C/D layout col=lane&15, row=quad*4+reg (m89/m91-verified)
#pragma unroll
    for (int ni = 0; ni < 2; ++ni) {
        const int col = n0 + wn + ni * 16 + l15;
        const float bb = bias[col] * bscale;
#pragma unroll
        for (int mi = 0; mi < 2; ++mi) {
            const int row = m0 + wm + mi * 16 + quad * 4;
#pragma unroll
            for (int r = 0; r < 4; ++r) {
                Y[(size_t)(row + r) * D_SZ + col] = acc[mi][ni][r] + bb;
            }
        }
    }
}

// ---------------------------------------------------------------------------
// Kernel 2: out[b,i] = sum_j exp2(q_i*kL_j - m_i)*v_j / den, m_i exact via
// kmax/kmin of the (pre-log2-scaled) k row. One block per b, 256 thr,
// 2 rows/thread. Inner loop packed ACROSS j: {q,q}/{c,c} broadcast pairs are
// loop-invariant, so every j costs exactly 3 v_pk ops + 2 v_exp_f32.
// a/b accumulator streams break the dependency chains.
// ---------------------------------------------------------------------------
__global__ __launch_bounds__(256) void attn_kernel(
    const float* __restrict__ qkv, float* __restrict__ out)
{
    const int b = blockIdx.x;
    const int t = threadIdx.x;

    const float* __restrict__ q = qkv + (size_t)b * D_SZ;
    const float* __restrict__ k = qkv + (size_t)B_SZ * D_SZ + (size_t)b * D_SZ;       // already *log2e
    const float* __restrict__ v = qkv + (size_t)2 * B_SZ * D_SZ + (size_t)b * D_SZ;

    __shared__ __align__(16) float kk_s[D_SZ];
    __shared__ __align__(16) float vv_s[D_SZ];
    __shared__ float redmax[4], redmin[4];

    const int i0 = t, i1 = t + 256;
    const float q0 = q[i0];
    const float q1 = q[i1];

    float kmaxL = -3.0e38f, kminL = 3.0e38f;
#pragma unroll
    for (int j = t; j < D_SZ; j += 256) {
        float kj = k[j];
        float vj = v[j];
        kk_s[j] = kj;
        vv_s[j] = vj;
        kmaxL = fmaxf(kmaxL, kj);
        kminL = fminf(kminL, kj);
    }
#pragma unroll
    for (int off = 32; off > 0; off >>= 1) {
        kmaxL = fmaxf(kmaxL, __shfl_xor(kmaxL, off));
        kminL = fminf(kminL, __shfl_xor(kminL, off));
    }
    const int wave = t >> 6;
    if ((t & 63) == 0) { redmax[wave] = kmaxL; redmin[wave] = kminL; }
    __syncthreads();   // also publishes kk_s/vv_s
    kmaxL = fmaxf(fmaxf(redmax[0], redmax[1]), fmaxf(redmax[2], redmax[3]));
    kminL = fminf(fminf(redmin[0], redmin[1]), fminf(redmin[2], redmin[3]));

    const float c0 = (q0 >= 0.f) ? -(q0 * kmaxL) : -(q0 * kminL);
    const float c1 = (q1 >= 0.f) ? -(q1 * kmaxL) : -(q1 * kminL);

    const f32x2 q00 = {q0, q0}, q11 = {q1, q1};
    const f32x2 c00 = {c0, c0}, c11 = {c1, c1};

    f32x2 den0a = {0.f, 0.f}, den0b = {0.f, 0.f};
    f32x2 den1a = {0.f, 0.f}, den1b = {0.f, 0.f};
    f32x2 num0a = {0.f, 0.f}, num0b = {0.f, 0.f};
    f32x2 num1a = {0.f, 0.f}, num1b = {0.f, 0.f};

#pragma unroll 2
    for (int j = 0; j < D_SZ; j += 4) {
        f32x4 kq = *(const f32x4*)&kk_s[j];   // broadcast reads: conflict-free
        f32x4 vq = *(const f32x4*)&vv_s[j];
        f32x2 ka = {kq.x, kq.y}, kb = {kq.z, kq.w};
        f32x2 va = {vq.x, vq.y}, vb = {vq.z, vq.w};

        f32x2 a0a = pk_fma(q00, ka, c00);
        f32x2 a0b = pk_fma(q00, kb, c00);
        f32x2 a1a = pk_fma(q11, ka, c11);
        f32x2 a1b = pk_fma(q11, kb, c11);

        f32x2 e0a = {exp2_raw(a0a.x), exp2_raw(a0a.y)};
        f32x2 e0b = {exp2_raw(a0b.x), exp2_raw(a0b.y)};
        f32x2 e1a = {exp2_raw(a1a.x), exp2_raw(a1a.y)};
        f32x2 e1b = {exp2_raw(a1b.x), exp2_raw(a1b.y)};

        den0a = pk_add(den0a, e0a);
        den0b = pk_add(den0b, e0b);
        den1a = pk_add(den1a, e1a);
        den1b = pk_add(den1b, e1b);
        num0a = pk_fma(e0a, va, num0a);
        num0b = pk_fma(e0b, vb, num0b);
        num1a = pk_fma(e1a, va, num1a);
        num1b = pk_fma(e1b, vb, num1b);
    }

    const f32x2 den0p = pk_add(den0a, den0b);
    const f32x2 den1p = pk_add(den1a, den1b);
    const f32x2 num0p = pk_add(num0a, num0b);
    const f32x2 num1p = pk_add(num1a, num1b);
    const float den0 = den0p.x + den0p.y;
    const float den1 = den1p.x + den1p.y;
    const float num0 = num0p.x + num0p.y;
    const float num1 = num1p.x + num1p.y;

    out[(size_t)b * D_SZ + i0] = num0 / den0;
    out[(size_t)b * D_SZ + i1] = num1 / den1;
}

extern "C" void kernel_launch(void* const* d_in, const int* in_sizes, int n_in,
                              void* d_out, int out_size, void* d_ws, size_t ws_size,
                              hipStream_t stream) {
    const float* query = (const float*)d_in[0];
    const float* key_  = (const float*)d_in[1];
    const float* value = (const float*)d_in[2];
    const float* Wq    = (const float*)d_in[3];
    const float* bq    = (const float*)d_in[4];
    const float* Wk    = (const float*)d_in[5];
    const float* bk    = (const float*)d_in[6];
    const float* Wv    = (const float*)d_in[7];
    const float* bv    = (const float*)d_in[8];
    float* out = (float*)d_out;

    // workspace layout (28.3 MB total):
    float* qkv = (float*)d_ws;                                  // 3*B*D f32 = 12.58 MB
    unsigned short* xhi = (unsigned short*)(qkv + (size_t)3 * B_SZ * D_SZ);  // 6.29 MB
    unsigned short* xlo = xhi + (size_t)3 * B_SZ * D_SZ;                     // 6.29 MB
    unsigned short* whi = xlo + (size_t)3 * B_SZ * D_SZ;                     // 1.57 MB
    unsigned short* wlo = whi + (size_t)3 * D_SZ * D_SZ;                     // 1.57 MB

    dim3 g0(512, 1, 6);   // X needs 512 blocks/z, W early-outs past 128
    split_prepass<<<g0, 256, 0, stream>>>(query, key_, value, Wq, Wk, Wv,
                                          xhi, xlo, whi, wlo);

    dim3 g1(B_SZ / 64, D_SZ / 64, 3);
    qkv_gemm_mfma<<<g1, 256, 0, stream>>>(xhi, xlo, whi, wlo, bq, bk, bv, qkv);

    attn_kernel<<<B_SZ, 256, 0, stream>>>(qkv, out);
}

// Round 2
// 153.581 us; speedup vs baseline: 1.0229x; 1.0229x over previous
//
#include <hip/hip_runtime.h>

// Problem: B=2048, D=512, all fp32.
// q = query@Wq.T+bq ; k,v likewise. attn[b,i,j]=q_i*k_j (rank-1!),
// softmax over j, out[b,i] = sum_j softmax_j(q_i*k_j)*v_j.
//
// Round 6:
//  - attn: exp2 applied IN PLACE on the v_pk_fma result pair (a.x=exp2(a.x))
//    so results stay in the paired VGPRs -> no packing v_movs before the
//    pk_add/pk_fma accumulates. (Round-5's {exp2(a.x),exp2(a.y)} built a NEW
//    vector from extracts -> ~16 mov cycles per 512 pairs, eating the win.)
//  - GEMM: BK 32 -> 64. Halves barrier events (16 vs 32 per block), doubles
//    per-phase MFMA cover (24 MFMA + 16 frag b128 reads) over the global
//    prefetch. LDS rows padded to 72 shorts (144 B): both staging writes and
//    frag reads are bank-uniform (contiguous-equivalent).
//  - split_prepass unchanged (one-time fp32 -> hi/lo bf16; Wk,bk pre-scaled
//    by log2e so k lands in log2 domain).

#define B_SZ 2048
#define D_SZ 512
#define LOG2E 1.44269504088896340736f

typedef __attribute__((ext_vector_type(2))) float  f32x2;
typedef __attribute__((ext_vector_type(4))) float  f32x4;
typedef __attribute__((ext_vector_type(8))) short  bf16x8;   // MFMA A/B carrier
typedef __attribute__((ext_vector_type(4))) unsigned short u16x4;
typedef __attribute__((ext_vector_type(8))) unsigned short u16x8;

__device__ __forceinline__ float exp2_raw(float x) {
#if defined(__has_builtin) && __has_builtin(__builtin_amdgcn_exp2f)
    return __builtin_amdgcn_exp2f(x);
#else
    return exp2f(x);
#endif
}

// Forced packed fp32 math (compiler emits scalar for f32x2 exprs otherwise).
__device__ __forceinline__ f32x2 pk_fma(f32x2 a, f32x2 b, f32x2 c) {
    f32x2 d;
    asm("v_pk_fma_f32 %0, %1, %2, %3" : "=v"(d) : "v"(a), "v"(b), "v"(c));
    return d;
}
__device__ __forceinline__ f32x2 pk_add(f32x2 a, f32x2 b) {
    f32x2 d;
    asm("v_pk_add_f32 %0, %1, %2" : "=v"(d) : "v"(a), "v"(b));
    return d;
}

// Truncation split: hi = top 16 bits of fp32; lo = bf16(trunc) of residual.
// |x - hi - lo| <= 2^-14 |x|
__device__ __forceinline__ void split1(float x, unsigned short& hi, unsigned short& lo) {
    unsigned int u = __float_as_uint(x);
    hi = (unsigned short)(u >> 16);
    float r = x - __uint_as_float(u & 0xFFFF0000u);
    lo = (unsigned short)(__float_as_uint(r) >> 16);
}

__device__ __forceinline__ void split4(const float4& x, u16x4& h, u16x4& l) {
    unsigned short hh, ll;
    split1(x.x, hh, ll); h.x = hh; l.x = ll;
    split1(x.y, hh, ll); h.y = hh; l.y = ll;
    split1(x.z, hh, ll); h.z = hh; l.z = ll;
    split1(x.w, hh, ll); h.w = hh; l.w = ll;
}

// ---------------------------------------------------------------------------
// Kernel 0: one-time hi/lo split of X (query,key,value) and W (Wq,Wk,Wv).
// z = 0..2 -> X inputs (2048x512), z = 3..5 -> W (512x512). z==4 (Wk) is
// pre-scaled by log2(e) so the GEMM emits k already in log2 domain.
// ---------------------------------------------------------------------------
__global__ __launch_bounds__(256) void split_prepass(
    const float* __restrict__ Xq, const float* __restrict__ Xk, const float* __restrict__ Xv,
    const float* __restrict__ Wq, const float* __restrict__ Wk, const float* __restrict__ Wv,
    unsigned short* __restrict__ xhi, unsigned short* __restrict__ xlo,
    unsigned short* __restrict__ whi, unsigned short* __restrict__ wlo)
{
    const int z = blockIdx.z;
    const bool isW = (z >= 3);
    if (isW && blockIdx.x >= 128) return;   // W needs only 128 blocks

    const float* __restrict__ src =
        (z == 0) ? Xq : (z == 1) ? Xk : (z == 2) ? Xv :
        (z == 3) ? Wq : (z == 4) ? Wk : Wv;
    unsigned short* dh;
    unsigned short* dl;
    if (!isW) { size_t o = (size_t)z * B_SZ * D_SZ;       dh = xhi + o; dl = xlo + o; }
    else      { size_t o = (size_t)(z - 3) * D_SZ * D_SZ; dh = whi + o; dl = wlo + o; }

    const size_t i = ((size_t)blockIdx.x * 256 + threadIdx.x) * 8;
    const float s = (z == 4) ? LOG2E : 1.0f;

    float4 a = *(const float4*)(src + i);
    float4 b = *(const float4*)(src + i + 4);
    a.x *= s; a.y *= s; a.z *= s; a.w *= s;
    b.x *= s; b.y *= s; b.z *= s; b.w *= s;

    u16x4 h0, l0, h1, l1;
    split4(a, h0, l0);
    split4(b, h1, l1);
    u16x8 hh = {h0.x, h0.y, h0.z, h0.w, h1.x, h1.y, h1.z, h1.w};
    u16x8 ll = {l0.x, l0.y, l0.z, l0.w, l1.x, l1.y, l1.z, l1.w};
    *(u16x8*)(dh + i) = hh;
    *(u16x8*)(dl + i) = ll;
}

// ---------------------------------------------------------------------------
// Kernel 1: Y = X @ W^T + bias via split-bf16 MFMA, staged from pre-split
// arrays. 64x64 tile per block, 256 thr = 4 waves in 2x2; each wave 2x2 frags
// of 16x16x32 MFMA, 3 terms (hi*hi + lo*hi + hi*lo) into one fp32 acc.
// BK=64: 8 K-chunks, 2 barriers each (16 total vs 32 at BK=32); per chunk
// per wave: 24 MFMA + 16 frag ds_read_b128 cover the 8 global prefetches.
// LDS rows padded to 72 shorts = 144 B: writes and frag reads bank-uniform.
// ---------------------------------------------------------------------------
__global__ __launch_bounds__(256) void qkv_gemm_mfma(
    const unsigned short* __restrict__ xhi, const unsigned short* __restrict__ xlo,
    const unsigned short* __restrict__ whi, const unsigned short* __restrict__ wlo,
    const float* __restrict__ bq, const float* __restrict__ bk, const float* __restrict__ bv,
    float* __restrict__ qkv_out)
{
    const int which = blockIdx.z;
    const unsigned short* __restrict__ Ah = xhi + (size_t)which * B_SZ * D_SZ;
    const unsigned short* __restrict__ Al = xlo + (size_t)which * B_SZ * D_SZ;
    const unsigned short* __restrict__ Bh = whi + (size_t)which * D_SZ * D_SZ;
    const unsigned short* __restrict__ Bl = wlo + (size_t)which * D_SZ * D_SZ;
    const float* __restrict__ bias = (which == 0) ? bq : (which == 1) ? bk : bv;
    const float bscale = (which == 1) ? LOG2E : 1.0f;   // k: W pre-scaled, bias too
    float* __restrict__ Y = qkv_out + (size_t)which * B_SZ * D_SZ;

    const int t    = threadIdx.x;
    const int lane = t & 63;
    const int wv   = t >> 6;
    const int l15  = lane & 15;
    const int quad = lane >> 4;
    const int wm   = (wv >> 1) * 32;
    const int wn   = (wv & 1) * 32;
    const int m0   = blockIdx.x * 64;
    const int n0   = blockIdx.y * 64;

    __shared__ unsigned short Ahi[64][72], Alo[64][72];
    __shared__ unsigned short Bhi[64][72], Blo[64][72];

    f32x4 acc[2][2] = {{{0.f,0.f,0.f,0.f},{0.f,0.f,0.f,0.f}},
                       {{0.f,0.f,0.f,0.f},{0.f,0.f,0.f,0.f}}};

    // staging: 64 rows x 8 granules(16B) per array; thread -> row r, 2 granules
    const int r  = t >> 2;           // 0..63
    const int cs = (t & 3) * 16;     // short col base: 0,16,32,48

    const unsigned short* pAh = Ah + (size_t)(m0 + r) * D_SZ + cs;
    const unsigned short* pAl = Al + (size_t)(m0 + r) * D_SZ + cs;
    const unsigned short* pBh = Bh + (size_t)(n0 + r) * D_SZ + cs;
    const unsigned short* pBl = Bl + (size_t)(n0 + r) * D_SZ + cs;

    u16x8 rah0 = *(const u16x8*)(pAh);
    u16x8 rah1 = *(const u16x8*)(pAh + 8);
    u16x8 ral0 = *(const u16x8*)(pAl);
    u16x8 ral1 = *(const u16x8*)(pAl + 8);
    u16x8 rbh0 = *(const u16x8*)(pBh);
    u16x8 rbh1 = *(const u16x8*)(pBh + 8);
    u16x8 rbl0 = *(const u16x8*)(pBl);
    u16x8 rbl1 = *(const u16x8*)(pBl + 8);

    for (int kk = 0; kk < D_SZ; kk += 64) {
        __syncthreads();   // previous chunk's LDS fully consumed

        *(u16x8*)&Ahi[r][cs]     = rah0;
        *(u16x8*)&Ahi[r][cs + 8] = rah1;
        *(u16x8*)&Alo[r][cs]     = ral0;
        *(u16x8*)&Alo[r][cs + 8] = ral1;
        *(u16x8*)&Bhi[r][cs]     = rbh0;
        *(u16x8*)&Bhi[r][cs + 8] = rbh1;
        *(u16x8*)&Blo[r][cs]     = rbl0;
        *(u16x8*)&Blo[r][cs + 8] = rbl1;

        __syncthreads();

        // prefetch next chunk (24 MFMA + 16 b128 frag reads below hide it)
        if (kk + 64 < D_SZ) {
            rah0 = *(const u16x8*)(pAh + kk + 64);
            rah1 = *(const u16x8*)(pAh + kk + 72);
            ral0 = *(const u16x8*)(pAl + kk + 64);
            ral1 = *(const u16x8*)(pAl + kk + 72);
            rbh0 = *(const u16x8*)(pBh + kk + 64);
            rbh1 = *(const u16x8*)(pBh + kk + 72);
            rbl0 = *(const u16x8*)(pBl + kk + 64);
            rbl1 = *(const u16x8*)(pBl + kk + 72);
        }

#pragma unroll
        for (int ks = 0; ks < 2; ++ks) {
            const int co = ks * 32 + quad * 8;   // short col of this frag
            // fragment loads: A[m=lane&15][k=quad*8+j] (m89/m120-verified)
            bf16x8 ah0 = *(const bf16x8*)&Ahi[wm + l15     ][co];
            bf16x8 ah1 = *(const bf16x8*)&Ahi[wm + 16 + l15][co];
            bf16x8 al0 = *(const bf16x8*)&Alo[wm + l15     ][co];
            bf16x8 al1 = *(const bf16x8*)&Alo[wm + 16 + l15][co];
            bf16x8 bh0 = *(const bf16x8*)&Bhi[wn + l15     ][co];
            bf16x8 bh1 = *(const bf16x8*)&Bhi[wn + 16 + l15][co];
            bf16x8 bl0 = *(const bf16x8*)&Blo[wn + l15     ][co];
            bf16x8 bl1 = *(const bf16x8*)&Blo[wn + 16 + l15][co];

            acc[0][0] = __builtin_amdgcn_mfma_f32_16x16x32_bf16(ah0, bh0, acc[0][0], 0, 0, 0);
            acc[0][0] = __builtin_amdgcn_mfma_f32_16x16x32_bf16(al0, bh0, acc[0][0], 0, 0, 0);
            acc[0][0] = __builtin_amdgcn_mfma_f32_16x16x32_bf16(ah0, bl0, acc[0][0], 0, 0, 0);
            acc[0][1] = __builtin_amdgcn_mfma_f32_16x16x32_bf16(ah0, bh1, acc[0][1], 0, 0, 0);
            acc[0][1] = __builtin_amdgcn_mfma_f32_16x16x32_bf16(al0, bh1, acc[0][1], 0, 0, 0);
            acc[0][1] = __builtin_amdgcn_mfma_f32_16x16x32_bf16(ah0, bl1, acc[0][1], 0, 0, 0);
            acc[1][0] = __builtin_amdgcn_mfma_f32_16x16x32_bf16(ah1, bh0, acc[1][0], 0, 0, 0);
            acc[1][0] = __builtin_amdgcn_mfma_f32_16x16x32_bf16(al1, bh0, acc[1][0], 0, 0, 0);
            acc[1][0] = __builtin_amdgcn_mfma_f32_16x16x32_bf16(ah1, bl0, acc[1][0], 0, 0, 0);
            acc[1][1] = __builtin_amdgcn_mfma_f32_16x16x32_bf16(ah1, bh1, acc[1][1], 0, 0, 0);
            acc[1][1] = __builtin_amdgcn_mfma_f32_16x16x32_bf16(al1, bh1, acc[1][1], 0, 0, 0);
            acc[1][1] = __builtin_amdgcn_mfma_f32_16x16x32_bf16(ah1, bl1, acc[1][1], 0, 0, 0);
        }
    }

    // epilogue: C/D layout col=lane&15, row=quad*4+reg (m89/m91-verified)
#pragma unroll
    for (int ni = 0; ni < 2; ++ni) {
        const int col = n0 + wn + ni * 16 + l15;
        const float bb = bias[col] * bscale;
#pragma unroll
        for (int mi = 0; mi < 2; ++mi) {
            const int row = m0 + wm + mi * 16 + quad * 4;
#pragma unroll
            for (int rr = 0; rr < 4; ++rr) {
                Y[(size_t)(row + rr) * D_SZ + col] = acc[mi][ni][rr] + bb;
            }
        }
    }
}

// ---------------------------------------------------------------------------
// Kernel 2: out[b,i] = sum_j exp2(q_i*kL_j - m_i)*v_j / den, m_i exact via
// kmax/kmin of the (pre-log2-scaled) k row. One block per b, 256 thr,
// 2 rows/thread. Inner loop packed across j; exp2 runs IN PLACE on the
// pk_fma result pair so the pk_add/pk_fma consumers need no repack movs.
// ---------------------------------------------------------------------------
__global__ __launch_bounds__(256) void attn_kernel(
    const float* __restrict__ qkv, float* __restrict__ out)
{
    const int b = blockIdx.x;
    const int t = threadIdx.x;

    const float* __restrict__ q = qkv + (size_t)b * D_SZ;
    const float* __restrict__ k = qkv + (size_t)B_SZ * D_SZ + (size_t)b * D_SZ;   // already *log2e
    const float* __restrict__ v = qkv + (size_t)2 * B_SZ * D_SZ + (size_t)b * D_SZ;

    __shared__ __align__(16) float kk_s[D_SZ];
    __shared__ __align__(16) float vv_s[D_SZ];
    __shared__ float redmax[4], redmin[4];

    const int i0 = t, i1 = t + 256;
    const float q0 = q[i0];
    const float q1 = q[i1];

    float kmaxL = -3.0e38f, kminL = 3.0e38f;
#pragma unroll
    for (int j = t; j < D_SZ; j += 256) {
        float kj = k[j];
        float vj = v[j];
        kk_s[j] = kj;
        vv_s[j] = vj;
        kmaxL = fmaxf(kmaxL, kj);
        kminL = fminf(kminL, kj);
    }
#pragma unroll
    for (int off = 32; off > 0; off >>= 1) {
        kmaxL = fmaxf(kmaxL, __shfl_xor(kmaxL, off));
        kminL = fminf(kminL, __shfl_xor(kminL, off));
    }
    const int wave = t >> 6;
    if ((t & 63) == 0) { redmax[wave] = kmaxL; redmin[wave] = kminL; }
    __syncthreads();   // also publishes kk_s/vv_s
    kmaxL = fmaxf(fmaxf(redmax[0], redmax[1]), fmaxf(redmax[2], redmax[3]));
    kminL = fminf(fminf(redmin[0], redmin[1]), fminf(redmin[2], redmin[3]));

    const float c0 = (q0 >= 0.f) ? -(q0 * kmaxL) : -(q0 * kminL);
    const float c1 = (q1 >= 0.f) ? -(q1 * kmaxL) : -(q1 * kminL);

    const f32x2 q00 = {q0, q0}, q11 = {q1, q1};
    const f32x2 c00 = {c0, c0}, c11 = {c1, c1};

    f32x2 den0a = {0.f, 0.f}, den0b = {0.f, 0.f};
    f32x2 den1a = {0.f, 0.f}, den1b = {0.f, 0.f};
    f32x2 num0a = {0.f, 0.f}, num0b = {0.f, 0.f};
    f32x2 num1a = {0.f, 0.f}, num1b = {0.f, 0.f};

#pragma unroll 4
    for (int j = 0; j < D_SZ; j += 4) {
        f32x4 kq = *(const f32x4*)&kk_s[j];   // broadcast reads: conflict-free
        f32x4 vq = *(const f32x4*)&vv_s[j];
        f32x2 ka = {kq.x, kq.y}, kb = {kq.z, kq.w};
        f32x2 va = {vq.x, vq.y}, vb = {vq.z, vq.w};

        f32x2 e0a = pk_fma(q00, ka, c00);
        f32x2 e0b = pk_fma(q00, kb, c00);
        f32x2 e1a = pk_fma(q11, ka, c11);
        f32x2 e1b = pk_fma(q11, kb, c11);

        // in-place: v_exp_f32 vN, vN on the pair's own registers (no repack)
        e0a.x = exp2_raw(e0a.x); e0a.y = exp2_raw(e0a.y);
        e0b.x = exp2_raw(e0b.x); e0b.y = exp2_raw(e0b.y);
        e1a.x = exp2_raw(e1a.x); e1a.y = exp2_raw(e1a.y);
        e1b.x = exp2_raw(e1b.x); e1b.y = exp2_raw(e1b.y);

        den0a = pk_add(den0a, e0a);
        den0b = pk_add(den0b, e0b);
        den1a = pk_add(den1a, e1a);
        den1b = pk_add(den1b, e1b);
        num0a = pk_fma(e0a, va, num0a);
        num0b = pk_fma(e0b, vb, num0b);
        num1a = pk_fma(e1a, va, num1a);
        num1b = pk_fma(e1b, vb, num1b);
    }

    const f32x2 den0p = pk_add(den0a, den0b);
    const f32x2 den1p = pk_add(den1a, den1b);
    const f32x2 num0p = pk_add(num0a, num0b);
    const f32x2 num1p = pk_add(num1a, num1b);
    const float den0 = den0p.x + den0p.y;
    const float den1 = den1p.x + den1p.y;
    const float num0 = num0p.x + num0p.y;
    const float num1 = num1p.x + num1p.y;

    out[(size_t)b * D_SZ + i0] = num0 / den0;
    out[(size_t)b * D_SZ + i1] = num1 / den1;
}

extern "C" void kernel_launch(void* const* d_in, const int* in_sizes, int n_in,
                              void* d_out, int out_size, void* d_ws, size_t ws_size,
                              hipStream_t stream) {
    const float* query = (const float*)d_in[0];
    const float* key_  = (const float*)d_in[1];
    const float* value = (const float*)d_in[2];
    const float* Wq    = (const float*)d_in[3];
    const float* bq    = (const float*)d_in[4];
    const float* Wk    = (const float*)d_in[5];
    const float* bk    = (const float*)d_in[6];
    const float* Wv    = (const float*)d_in[7];
    const float* bv    = (const float*)d_in[8];
    float* out = (float*)d_out;

    // workspace layout (28.3 MB total):
    float* qkv = (float*)d_ws;                                  // 3*B*D f32 = 12.58 MB
    unsigned short* xhi = (unsigned short*)(qkv + (size_t)3 * B_SZ * D_SZ);  // 6.29 MB
    unsigned short* xlo = xhi + (size_t)3 * B_SZ * D_SZ;                     // 6.29 MB
    unsigned short* whi = xlo + (size_t)3 * B_SZ * D_SZ;                     // 1.57 MB
    unsigned short* wlo = whi + (size_t)3 * D_SZ * D_SZ;                     // 1.57 MB

    dim3 g0(512, 1, 6);   // X needs 512 blocks/z, W early-outs past 128
    split_prepass<<<g0, 256, 0, stream>>>(query, key_, value, Wq, Wk, Wv,
                                          xhi, xlo, whi, wlo);

    dim3 g1(B_SZ / 64, D_SZ / 64, 3);
    qkv_gemm_mfma<<<g1, 256, 0, stream>>>(xhi, xlo, whi, wlo, bq, bk, bv, qkv);

    attn_kernel<<<B_SZ, 256, 0, stream>>>(qkv, out);
}

// Round 3
// 113.853 us; speedup vs baseline: 1.3798x; 1.3489x over previous
//
#include <hip/hip_runtime.h>

// Problem: B=2048, D=512, all fp32.
// q = query@Wq.T+bq ; k,v likewise. attn[b,i,j]=q_i*k_j (rank-1!),
// softmax over j, out[b,i] = sum_j softmax_j(q_i*k_j)*v_j.
//
// Round 7:
//  - attn REWRITE: out[b,i] = f(q_i) with f(s) = sum_j e^{s k_j} v_j /
//    sum_j e^{s k_j} -- a smooth 1-D function per batch. Evaluate f on a
//    128-point uniform grid over [min_i q_i, max_i q_i] (128x512 exps,
//    4x fewer than 512x512), then Lagrange-cubic interpolate per q_i.
//    Interp error <= h^4 |f''''|/384 ~ 1e-5..2e-4, invisible vs the 2^-7
//    split-GEMM error. Max-shift dropped (args <= ~35, exp2-safe; softmax
//    shift-invariant). Trans-pipe work drops 4x; VALU per-exp unchanged.
//  - GEMM + prepass byte-identical to round 6 (isolate the attn change;
//    gemm becomes top-5-visible next round for direct diagnosis).

#define B_SZ 2048
#define D_SZ 512
#define LOG2E 1.44269504088896340736f
#define NGRID 128

typedef __attribute__((ext_vector_type(2))) float  f32x2;
typedef __attribute__((ext_vector_type(4))) float  f32x4;
typedef __attribute__((ext_vector_type(8))) short  bf16x8;   // MFMA A/B carrier
typedef __attribute__((ext_vector_type(4))) unsigned short u16x4;
typedef __attribute__((ext_vector_type(8))) unsigned short u16x8;

__device__ __forceinline__ float exp2_raw(float x) {
#if defined(__has_builtin) && __has_builtin(__builtin_amdgcn_exp2f)
    return __builtin_amdgcn_exp2f(x);
#else
    return exp2f(x);
#endif
}

// Forced packed fp32 math (compiler emits scalar for f32x2 exprs otherwise).
__device__ __forceinline__ f32x2 pk_fma(f32x2 a, f32x2 b, f32x2 c) {
    f32x2 d;
    asm("v_pk_fma_f32 %0, %1, %2, %3" : "=v"(d) : "v"(a), "v"(b), "v"(c));
    return d;
}
__device__ __forceinline__ f32x2 pk_add(f32x2 a, f32x2 b) {
    f32x2 d;
    asm("v_pk_add_f32 %0, %1, %2" : "=v"(d) : "v"(a), "v"(b));
    return d;
}
__device__ __forceinline__ f32x2 pk_mul(f32x2 a, f32x2 b) {
    f32x2 d;
    asm("v_pk_mul_f32 %0, %1, %2" : "=v"(d) : "v"(a), "v"(b));
    return d;
}

// Truncation split: hi = top 16 bits of fp32; lo = bf16(trunc) of residual.
// |x - hi - lo| <= 2^-14 |x|
__device__ __forceinline__ void split1(float x, unsigned short& hi, unsigned short& lo) {
    unsigned int u = __float_as_uint(x);
    hi = (unsigned short)(u >> 16);
    float r = x - __uint_as_float(u & 0xFFFF0000u);
    lo = (unsigned short)(__float_as_uint(r) >> 16);
}

__device__ __forceinline__ void split4(const float4& x, u16x4& h, u16x4& l) {
    unsigned short hh, ll;
    split1(x.x, hh, ll); h.x = hh; l.x = ll;
    split1(x.y, hh, ll); h.y = hh; l.y = ll;
    split1(x.z, hh, ll); h.z = hh; l.z = ll;
    split1(x.w, hh, ll); h.w = hh; l.w = ll;
}

// ---------------------------------------------------------------------------
// Kernel 0: one-time hi/lo split of X (query,key,value) and W (Wq,Wk,Wv).
// z = 0..2 -> X inputs (2048x512), z = 3..5 -> W (512x512). z==4 (Wk) is
// pre-scaled by log2(e) so the GEMM emits k already in log2 domain.
// ---------------------------------------------------------------------------
__global__ __launch_bounds__(256) void split_prepass(
    const float* __restrict__ Xq, const float* __restrict__ Xk, const float* __restrict__ Xv,
    const float* __restrict__ Wq, const float* __restrict__ Wk, const float* __restrict__ Wv,
    unsigned short* __restrict__ xhi, unsigned short* __restrict__ xlo,
    unsigned short* __restrict__ whi, unsigned short* __restrict__ wlo)
{
    const int z = blockIdx.z;
    const bool isW = (z >= 3);
    if (isW && blockIdx.x >= 128) return;   // W needs only 128 blocks

    const float* __restrict__ src =
        (z == 0) ? Xq : (z == 1) ? Xk : (z == 2) ? Xv :
        (z == 3) ? Wq : (z == 4) ? Wk : Wv;
    unsigned short* dh;
    unsigned short* dl;
    if (!isW) { size_t o = (size_t)z * B_SZ * D_SZ;       dh = xhi + o; dl = xlo + o; }
    else      { size_t o = (size_t)(z - 3) * D_SZ * D_SZ; dh = whi + o; dl = wlo + o; }

    const size_t i = ((size_t)blockIdx.x * 256 + threadIdx.x) * 8;
    const float s = (z == 4) ? LOG2E : 1.0f;

    float4 a = *(const float4*)(src + i);
    float4 b = *(const float4*)(src + i + 4);
    a.x *= s; a.y *= s; a.z *= s; a.w *= s;
    b.x *= s; b.y *= s; b.z *= s; b.w *= s;

    u16x4 h0, l0, h1, l1;
    split4(a, h0, l0);
    split4(b, h1, l1);
    u16x8 hh = {h0.x, h0.y, h0.z, h0.w, h1.x, h1.y, h1.z, h1.w};
    u16x8 ll = {l0.x, l0.y, l0.z, l0.w, l1.x, l1.y, l1.z, l1.w};
    *(u16x8*)(dh + i) = hh;
    *(u16x8*)(dl + i) = ll;
}

// ---------------------------------------------------------------------------
// Kernel 1: Y = X @ W^T + bias via split-bf16 MFMA, staged from pre-split
// arrays. 64x64 tile per block, 256 thr = 4 waves in 2x2; each wave 2x2 frags
// of 16x16x32 MFMA, 3 terms (hi*hi + lo*hi + hi*lo) into one fp32 acc.
// BK=64: 8 K-chunks, 2 barriers each; per chunk per wave: 24 MFMA + 16 frag
// ds_read_b128 cover the 8 global prefetches. LDS rows padded to 72 shorts.
// (Byte-identical to round 6 -- control variable this round.)
// ---------------------------------------------------------------------------
__global__ __launch_bounds__(256) void qkv_gemm_mfma(
    const unsigned short* __restrict__ xhi, const unsigned short* __restrict__ xlo,
    const unsigned short* __restrict__ whi, const unsigned short* __restrict__ wlo,
    const float* __restrict__ bq, const float* __restrict__ bk, const float* __restrict__ bv,
    float* __restrict__ qkv_out)
{
    const int which = blockIdx.z;
    const unsigned short* __restrict__ Ah = xhi + (size_t)which * B_SZ * D_SZ;
    const unsigned short* __restrict__ Al = xlo + (size_t)which * B_SZ * D_SZ;
    const unsigned short* __restrict__ Bh = whi + (size_t)which * D_SZ * D_SZ;
    const unsigned short* __restrict__ Bl = wlo + (size_t)which * D_SZ * D_SZ;
    const float* __restrict__ bias = (which == 0) ? bq : (which == 1) ? bk : bv;
    const float bscale = (which == 1) ? LOG2E : 1.0f;   // k: W pre-scaled, bias too
    float* __restrict__ Y = qkv_out + (size_t)which * B_SZ * D_SZ;

    const int t    = threadIdx.x;
    const int lane = t & 63;
    const int wv   = t >> 6;
    const int l15  = lane & 15;
    const int quad = lane >> 4;
    const int wm   = (wv >> 1) * 32;
    const int wn   = (wv & 1) * 32;
    const int m0   = blockIdx.x * 64;
    const int n0   = blockIdx.y * 64;

    __shared__ unsigned short Ahi[64][72], Alo[64][72];
    __shared__ unsigned short Bhi[64][72], Blo[64][72];

    f32x4 acc[2][2] = {{{0.f,0.f,0.f,0.f},{0.f,0.f,0.f,0.f}},
                       {{0.f,0.f,0.f,0.f},{0.f,0.f,0.f,0.f}}};

    // staging: 64 rows x 8 granules(16B) per array; thread -> row r, 2 granules
    const int r  = t >> 2;           // 0..63
    const int cs = (t & 3) * 16;     // short col base: 0,16,32,48

    const unsigned short* pAh = Ah + (size_t)(m0 + r) * D_SZ + cs;
    const unsigned short* pAl = Al + (size_t)(m0 + r) * D_SZ + cs;
    const unsigned short* pBh = Bh + (size_t)(n0 + r) * D_SZ + cs;
    const unsigned short* pBl = Bl + (size_t)(n0 + r) * D_SZ + cs;

    u16x8 rah0 = *(const u16x8*)(pAh);
    u16x8 rah1 = *(const u16x8*)(pAh + 8);
    u16x8 ral0 = *(const u16x8*)(pAl);
    u16x8 ral1 = *(const u16x8*)(pAl + 8);
    u16x8 rbh0 = *(const u16x8*)(pBh);
    u16x8 rbh1 = *(const u16x8*)(pBh + 8);
    u16x8 rbl0 = *(const u16x8*)(pBl);
    u16x8 rbl1 = *(const u16x8*)(pBl + 8);

    for (int kk = 0; kk < D_SZ; kk += 64) {
        __syncthreads();   // previous chunk's LDS fully consumed

        *(u16x8*)&Ahi[r][cs]     = rah0;
        *(u16x8*)&Ahi[r][cs + 8] = rah1;
        *(u16x8*)&Alo[r][cs]     = ral0;
        *(u16x8*)&Alo[r][cs + 8] = ral1;
        *(u16x8*)&Bhi[r][cs]     = rbh0;
        *(u16x8*)&Bhi[r][cs + 8] = rbh1;
        *(u16x8*)&Blo[r][cs]     = rbl0;
        *(u16x8*)&Blo[r][cs + 8] = rbl1;

        __syncthreads();

        // prefetch next chunk (24 MFMA + 16 b128 frag reads below hide it)
        if (kk + 64 < D_SZ) {
            rah0 = *(const u16x8*)(pAh + kk + 64);
            rah1 = *(const u16x8*)(pAh + kk + 72);
            ral0 = *(const u16x8*)(pAl + kk + 64);
            ral1 = *(const u16x8*)(pAl + kk + 72);
            rbh0 = *(const u16x8*)(pBh + kk + 64);
            rbh1 = *(const u16x8*)(pBh + kk + 72);
            rbl0 = *(const u16x8*)(pBl + kk + 64);
            rbl1 = *(const u16x8*)(pBl + kk + 72);
        }

#pragma unroll
        for (int ks = 0; ks < 2; ++ks) {
            const int co = ks * 32 + quad * 8;   // short col of this frag
            // fragment loads: A[m=lane&15][k=quad*8+j] (m89/m120-verified)
            bf16x8 ah0 = *(const bf16x8*)&Ahi[wm + l15     ][co];
            bf16x8 ah1 = *(const bf16x8*)&Ahi[wm + 16 + l15][co];
            bf16x8 al0 = *(const bf16x8*)&Alo[wm + l15     ][co];
            bf16x8 al1 = *(const bf16x8*)&Alo[wm + 16 + l15][co];
            bf16x8 bh0 = *(const bf16x8*)&Bhi[wn + l15     ][co];
            bf16x8 bh1 = *(const bf16x8*)&Bhi[wn + 16 + l15][co];
            bf16x8 bl0 = *(const bf16x8*)&Blo[wn + l15     ][co];
            bf16x8 bl1 = *(const bf16x8*)&Blo[wn + 16 + l15][co];

            acc[0][0] = __builtin_amdgcn_mfma_f32_16x16x32_bf16(ah0, bh0, acc[0][0], 0, 0, 0);
            acc[0][0] = __builtin_amdgcn_mfma_f32_16x16x32_bf16(al0, bh0, acc[0][0], 0, 0, 0);
            acc[0][0] = __builtin_amdgcn_mfma_f32_16x16x32_bf16(ah0, bl0, acc[0][0], 0, 0, 0);
            acc[0][1] = __builtin_amdgcn_mfma_f32_16x16x32_bf16(ah0, bh1, acc[0][1], 0, 0, 0);
            acc[0][1] = __builtin_amdgcn_mfma_f32_16x16x32_bf16(al0, bh1, acc[0][1], 0, 0, 0);
            acc[0][1] = __builtin_amdgcn_mfma_f32_16x16x32_bf16(ah0, bl1, acc[0][1], 0, 0, 0);
            acc[1][0] = __builtin_amdgcn_mfma_f32_16x16x32_bf16(ah1, bh0, acc[1][0], 0, 0, 0);
            acc[1][0] = __builtin_amdgcn_mfma_f32_16x16x32_bf16(al1, bh0, acc[1][0], 0, 0, 0);
            acc[1][0] = __builtin_amdgcn_mfma_f32_16x16x32_bf16(ah1, bl0, acc[1][0], 0, 0, 0);
            acc[1][1] = __builtin_amdgcn_mfma_f32_16x16x32_bf16(ah1, bh1, acc[1][1], 0, 0, 0);
            acc[1][1] = __builtin_amdgcn_mfma_f32_16x16x32_bf16(al1, bh1, acc[1][1], 0, 0, 0);
            acc[1][1] = __builtin_amdgcn_mfma_f32_16x16x32_bf16(ah1, bl1, acc[1][1], 0, 0, 0);
        }
    }

    // epilogue: C/D layout col=lane&15, row=quad*4+reg (m89/m91-verified)
#pragma unroll
    for (int ni = 0; ni < 2; ++ni) {
        const int col = n0 + wn + ni * 16 + l15;
        const float bb = bias[col] * bscale;
#pragma unroll
        for (int mi = 0; mi < 2; ++mi) {
            const int row = m0 + wm + mi * 16 + quad * 4;
#pragma unroll
            for (int rr = 0; rr < 4; ++rr) {
                Y[(size_t)(row + rr) * D_SZ + col] = acc[mi][ni][rr] + bb;
            }
        }
    }
}

// ---------------------------------------------------------------------------
// Kernel 2 (REWRITE): per batch b, f(s) = sum_j exp2(s*kL_j)*v_j /
// sum_j exp2(s*kL_j) is a smooth scalar function; out[b,i] = f(q_i).
// Phase 1: evaluate f on a 128-pt uniform grid over [qmin,qmax].
//   thread pairs (2g, 2g+1) share grid point g, each sweeps 256 j's,
//   shfl_xor(1) combines. 128x512 exps per block (4x fewer than 512x512).
// Phase 2: Lagrange-cubic interpolation of fgrid at each q_i (2 i/thread).
// No max-shift: |s*kL| <= ~35 << 127, exp2-range-safe.
// ---------------------------------------------------------------------------
__global__ __launch_bounds__(256) void attn_kernel(
    const float* __restrict__ qkv, float* __restrict__ out)
{
    const int b = blockIdx.x;
    const int t = threadIdx.x;

    const float* __restrict__ q = qkv + (size_t)b * D_SZ;
    const float* __restrict__ k = qkv + (size_t)B_SZ * D_SZ + (size_t)b * D_SZ;   // already *log2e
    const float* __restrict__ v = qkv + (size_t)2 * B_SZ * D_SZ + (size_t)b * D_SZ;

    __shared__ __align__(16) float kk_s[D_SZ];
    __shared__ __align__(16) float vv_s[D_SZ];
    __shared__ __align__(16) float fgrid[NGRID];
    __shared__ float redmax[4], redmin[4];

    // ---- stage k,v to LDS (float2 per thread), load this thread's q rows ----
    const int i0 = t, i1 = t + 256;
    const float q0 = q[i0];
    const float q1 = q[i1];
    {
        float2 kf = *(const float2*)&k[2 * t];
        float2 vf = *(const float2*)&v[2 * t];
        *(float2*)&kk_s[2 * t] = kf;
        *(float2*)&vv_s[2 * t] = vf;
    }

    // ---- q-range reduction (grid support) ----
    float qmax = fmaxf(q0, q1), qmin = fminf(q0, q1);
#pragma unroll
    for (int off = 32; off > 0; off >>= 1) {
        qmax = fmaxf(qmax, __shfl_xor(qmax, off));
        qmin = fminf(qmin, __shfl_xor(qmin, off));
    }
    const int wave = t >> 6;
    if ((t & 63) == 0) { redmax[wave] = qmax; redmin[wave] = qmin; }
    __syncthreads();   // also publishes kk_s/vv_s
    qmax = fmaxf(fmaxf(redmax[0], redmax[1]), fmaxf(redmax[2], redmax[3]));
    qmin = fminf(fminf(redmin[0], redmin[1]), fminf(redmin[2], redmin[3]));

    const float h    = fmaxf((qmax - qmin) * (1.0f / (float)(NGRID - 3)), 1e-30f);
    const float s0   = qmin - h;                 // grid: s_g = s0 + g*h, g=0..127
    const float invh = 1.0f / h;                 // q in [s_1, s_126]

    // ---- phase 1: grid evaluation ----
    {
        const int   g   = t >> 1;
        const int   jb  = (t & 1) * 256;
        const float sg  = s0 + (float)g * h;
        const f32x2 sgg = {sg, sg};

        f32x2 dena = {0.f, 0.f}, denb = {0.f, 0.f};
        f32x2 numa = {0.f, 0.f}, numb = {0.f, 0.f};
#pragma unroll 4
        for (int jj = 0; jj < 256; jj += 4) {
            f32x4 kq = *(const f32x4*)&kk_s[jb + jj];   // broadcast: conflict-free
            f32x4 vq = *(const f32x4*)&vv_s[jb + jj];
            f32x2 ka = {kq.x, kq.y}, kb_ = {kq.z, kq.w};
            f32x2 va = {vq.x, vq.y}, vb_ = {vq.z, vq.w};

            f32x2 ea = pk_mul(sgg, ka);
            f32x2 eb = pk_mul(sgg, kb_);
            // in-place v_exp_f32 on the pair's own registers (no repack)
            ea.x = exp2_raw(ea.x); ea.y = exp2_raw(ea.y);
            eb.x = exp2_raw(eb.x); eb.y = exp2_raw(eb.y);

            dena = pk_add(dena, ea);
            denb = pk_add(denb, eb);
            numa = pk_fma(ea, va, numa);
            numb = pk_fma(eb, vb_, numb);
        }
        float den = (dena.x + dena.y) + (denb.x + denb.y);
        float num = (numa.x + numa.y) + (numb.x + numb.y);
        den += __shfl_xor(den, 1);
        num += __shfl_xor(num, 1);
        if ((t & 1) == 0) fgrid[g] = num / den;
    }
    __syncthreads();

    // ---- phase 2: cubic interpolation at q_i ----
#pragma unroll
    for (int r = 0; r < 2; ++r) {
        const float qi = (r == 0) ? q0 : q1;
        const int   ii = (r == 0) ? i0 : i1;

        float u  = (qi - s0) * invh;
        int   ic = (int)floorf(u);
        ic = (ic < 1) ? 1 : ((ic > NGRID - 3) ? (NGRID - 3) : ic);
        float uu = u - (float)ic;

        float f0 = fgrid[ic - 1];
        float f1 = fgrid[ic];
        float f2 = fgrid[ic + 1];
        float f3 = fgrid[ic + 2];

        const float um1 = uu - 1.0f, um2 = uu - 2.0f, up1 = uu + 1.0f;
        const float w0 = -uu * um1 * um2 * (1.0f / 6.0f);
        const float w1 =  up1 * um1 * um2 * 0.5f;
        const float w2 = -up1 * uu  * um2 * 0.5f;
        const float w3 =  up1 * uu  * um1 * (1.0f / 6.0f);

        out[(size_t)b * D_SZ + ii] = w0 * f0 + w1 * f1 + w2 * f2 + w3 * f3;
    }
}

extern "C" void kernel_launch(void* const* d_in, const int* in_sizes, int n_in,
                              void* d_out, int out_size, void* d_ws, size_t ws_size,
                              hipStream_t stream) {
    const float* query = (const float*)d_in[0];
    const float* key_  = (const float*)d_in[1];
    const float* value = (const float*)d_in[2];
    const float* Wq    = (const float*)d_in[3];
    const float* bq    = (const float*)d_in[4];
    const float* Wk    = (const float*)d_in[5];
    const float* bk    = (const float*)d_in[6];
    const float* Wv    = (const float*)d_in[7];
    const float* bv    = (const float*)d_in[8];
    float* out = (float*)d_out;

    // workspace layout (28.3 MB total):
    float* qkv = (float*)d_ws;                                  // 3*B*D f32 = 12.58 MB
    unsigned short* xhi = (unsigned short*)(qkv + (size_t)3 * B_SZ * D_SZ);  // 6.29 MB
    unsigned short* xlo = xhi + (size_t)3 * B_SZ * D_SZ;                     // 6.29 MB
    unsigned short* whi = xlo + (size_t)3 * B_SZ * D_SZ;                     // 1.57 MB
    unsigned short* wlo = whi + (size_t)3 * D_SZ * D_SZ;                     // 1.57 MB

    dim3 g0(512, 1, 6);   // X needs 512 blocks/z, W early-outs past 128
    split_prepass<<<g0, 256, 0, stream>>>(query, key_, value, Wq, Wk, Wv,
                                          xhi, xlo, whi, wlo);

    dim3 g1(B_SZ / 64, D_SZ / 64, 3);
    qkv_gemm_mfma<<<g1, 256, 0, stream>>>(xhi, xlo, whi, wlo, bq, bk, bv, qkv);

    attn_kernel<<<B_SZ, 256, 0, stream>>>(qkv, out);
}

// Round 4
// 111.113 us; speedup vs baseline: 1.4138x; 1.0247x over previous
//
#include <hip/hip_runtime.h>

// Problem: B=2048, D=512, all fp32.
// q = query@Wq.T+bq ; k,v likewise. attn[b,i,j]=q_i*k_j (rank-1!),
// softmax over j, out[b,i] = sum_j softmax_j(q_i*k_j)*v_j.
//
// Round 8:
//  - GEMM REWRITE (m97 pattern): 128x128 tile, BK=32, double-buffered LDS,
//    staging via global_load_lds width=16 (async DMA, no VGPR roundtrip, no
//    ds_write). One __syncthreads per K-step; its auto vmcnt(0)+lgkm drain
//    is the only wait and sits after 48 MFMAs of cover. 192 blocks, 4 waves,
//    each wave owns 64x64 via 4x4 16x16x32 frags, 3-term split-bf16.
//  - attn: NGRID 64 (4 threads per grid point); k/v LDS in 4x136-float
//    segments so the wave's 4 distinct 16B addresses hit distinct bank
//    groups (round-7 had them all on bank 0: 4-way serialize).
//  - split_prepass unchanged.

#define B_SZ 2048
#define D_SZ 512
#define LOG2E 1.44269504088896340736f
#define NGRID 64
#define SEG 136   // 128 floats payload + 8 pad: segment s starts at bank 8s

typedef __attribute__((ext_vector_type(2))) float  f32x2;
typedef __attribute__((ext_vector_type(4))) float  f32x4;
typedef __attribute__((ext_vector_type(8))) short  bf16x8;   // MFMA A/B carrier
typedef __attribute__((ext_vector_type(4))) unsigned short u16x4;
typedef __attribute__((ext_vector_type(8))) unsigned short u16x8;

__device__ __forceinline__ float exp2_raw(float x) {
#if defined(__has_builtin) && __has_builtin(__builtin_amdgcn_exp2f)
    return __builtin_amdgcn_exp2f(x);
#else
    return exp2f(x);
#endif
}

// Forced packed fp32 math (compiler emits scalar for f32x2 exprs otherwise).
__device__ __forceinline__ f32x2 pk_fma(f32x2 a, f32x2 b, f32x2 c) {
    f32x2 d;
    asm("v_pk_fma_f32 %0, %1, %2, %3" : "=v"(d) : "v"(a), "v"(b), "v"(c));
    return d;
}
__device__ __forceinline__ f32x2 pk_add(f32x2 a, f32x2 b) {
    f32x2 d;
    asm("v_pk_add_f32 %0, %1, %2" : "=v"(d) : "v"(a), "v"(b));
    return d;
}
__device__ __forceinline__ f32x2 pk_mul(f32x2 a, f32x2 b) {
    f32x2 d;
    asm("v_pk_mul_f32 %0, %1, %2" : "=v"(d) : "v"(a), "v"(b));
    return d;
}

// async global->LDS, 16B per lane. lds ptr must be wave-uniform (HW adds
// lane*16). Guide: m97/m193 pattern, size must be a literal.
__device__ __forceinline__ void gload16(const void* g, void* l) {
    __builtin_amdgcn_global_load_lds(
        (const __attribute__((address_space(1))) unsigned int*)g,
        (__attribute__((address_space(3))) unsigned int*)l,
        16, 0, 0);
}

// Truncation split: hi = top 16 bits of fp32; lo = bf16(trunc) of residual.
// |x - hi - lo| <= 2^-14 |x|
__device__ __forceinline__ void split1(float x, unsigned short& hi, unsigned short& lo) {
    unsigned int u = __float_as_uint(x);
    hi = (unsigned short)(u >> 16);
    float r = x - __uint_as_float(u & 0xFFFF0000u);
    lo = (unsigned short)(__float_as_uint(r) >> 16);
}

__device__ __forceinline__ void split4(const float4& x, u16x4& h, u16x4& l) {
    unsigned short hh, ll;
    split1(x.x, hh, ll); h.x = hh; l.x = ll;
    split1(x.y, hh, ll); h.y = hh; l.y = ll;
    split1(x.z, hh, ll); h.z = hh; l.z = ll;
    split1(x.w, hh, ll); h.w = hh; l.w = ll;
}

// ---------------------------------------------------------------------------
// Kernel 0: one-time hi/lo split of X (query,key,value) and W (Wq,Wk,Wv).
// z = 0..2 -> X inputs (2048x512), z = 3..5 -> W (512x512). z==4 (Wk) is
// pre-scaled by log2(e) so the GEMM emits k already in log2 domain.
// ---------------------------------------------------------------------------
__global__ __launch_bounds__(256) void split_prepass(
    const float* __restrict__ Xq, const float* __restrict__ Xk, const float* __restrict__ Xv,
    const float* __restrict__ Wq, const float* __restrict__ Wk, const float* __restrict__ Wv,
    unsigned short* __restrict__ xhi, unsigned short* __restrict__ xlo,
    unsigned short* __restrict__ whi, unsigned short* __restrict__ wlo)
{
    const int z = blockIdx.z;
    const bool isW = (z >= 3);
    if (isW && blockIdx.x >= 128) return;   // W needs only 128 blocks

    const float* __restrict__ src =
        (z == 0) ? Xq : (z == 1) ? Xk : (z == 2) ? Xv :
        (z == 3) ? Wq : (z == 4) ? Wk : Wv;
    unsigned short* dh;
    unsigned short* dl;
    if (!isW) { size_t o = (size_t)z * B_SZ * D_SZ;       dh = xhi + o; dl = xlo + o; }
    else      { size_t o = (size_t)(z - 3) * D_SZ * D_SZ; dh = whi + o; dl = wlo + o; }

    const size_t i = ((size_t)blockIdx.x * 256 + threadIdx.x) * 8;
    const float s = (z == 4) ? LOG2E : 1.0f;

    float4 a = *(const float4*)(src + i);
    float4 b = *(const float4*)(src + i + 4);
    a.x *= s; a.y *= s; a.z *= s; a.w *= s;
    b.x *= s; b.y *= s; b.z *= s; b.w *= s;

    u16x4 h0, l0, h1, l1;
    split4(a, h0, l0);
    split4(b, h1, l1);
    u16x8 hh = {h0.x, h0.y, h0.z, h0.w, h1.x, h1.y, h1.z, h1.w};
    u16x8 ll = {l0.x, l0.y, l0.z, l0.w, l1.x, l1.y, l1.z, l1.w};
    *(u16x8*)(dh + i) = hh;
    *(u16x8*)(dl + i) = ll;
}

// ---------------------------------------------------------------------------
// Kernel 1: Y = X @ W^T + bias via split-bf16 MFMA.
// 128x128 tile, 256 thr = 4 waves (2x2, 64x64 each -> 4x4 frags of
// 16x16x32). BK=32, LDS [2 buf][4 slab:Ahi,Alo,Bhi,Blo][128][32] shorts
// = 64 KiB. Staging = 8 global_load_lds(16B)/thread/iter (async DMA,
// linear lane order). One __syncthreads per K-step (auto vmcnt drain).
// Frag reads: 64B rows -> banks balanced 8 lanes/group, conflict-free.
// ---------------------------------------------------------------------------
__global__ __launch_bounds__(256) void qkv_gemm_mfma(
    const unsigned short* __restrict__ xhi, const unsigned short* __restrict__ xlo,
    const unsigned short* __restrict__ whi, const unsigned short* __restrict__ wlo,
    const float* __restrict__ bq, const float* __restrict__ bk, const float* __restrict__ bv,
    float* __restrict__ qkv_out)
{
    const int which = blockIdx.z;
    const unsigned short* __restrict__ Ah = xhi + (size_t)which * B_SZ * D_SZ;
    const unsigned short* __restrict__ Al = xlo + (size_t)which * B_SZ * D_SZ;
    const unsigned short* __restrict__ Bh = whi + (size_t)which * D_SZ * D_SZ;
    const unsigned short* __restrict__ Bl = wlo + (size_t)which * D_SZ * D_SZ;
    const float* __restrict__ bias = (which == 0) ? bq : (which == 1) ? bk : bv;
    const float bscale = (which == 1) ? LOG2E : 1.0f;   // k: W pre-scaled, bias too
    float* __restrict__ Y = qkv_out + (size_t)which * B_SZ * D_SZ;

    const int t    = threadIdx.x;
    const int lane = t & 63;
    const int wv   = t >> 6;
    const int l15  = lane & 15;
    const int quad = lane >> 4;
    const int wm   = (wv >> 1) * 64;
    const int wn   = (wv & 1) * 64;
    const int m0   = blockIdx.x * 128;
    const int n0   = blockIdx.y * 128;

    // [buf][slab][row][k] ; slab: 0=Ahi 1=Alo 2=Bhi 3=Blo ; 65536 B total
    __shared__ unsigned short lds[2][4][128][32];

    f32x4 acc[4][4] = {};

    // staging geometry: lane L of wave w covers LDS bytes w*1024 + L*16 of
    // each (slab, half): row = h*64 + w*16 + L/4 = h*64 + (t>>2), chunk = t&3
    const int srow   = t >> 2;           // 0..63
    const int schunk = (t & 3) * 8;      // shorts
    char* lwave = (char*)&lds[0][0][0][0] + ((t >> 6) << 10);   // wave-uniform

    auto stage = [&](int cur, int kk) {
        char* lb = lwave + (size_t)cur * 32768;
#pragma unroll
        for (int h = 0; h < 2; ++h) {
            const size_t rA = (size_t)(m0 + h * 64 + srow) * D_SZ + kk + schunk;
            const size_t rB = (size_t)(n0 + h * 64 + srow) * D_SZ + kk + schunk;
            gload16(Ah + rA, lb +     0 + h * 4096);
            gload16(Al + rA, lb +  8192 + h * 4096);
            gload16(Bh + rB, lb + 16384 + h * 4096);
            gload16(Bl + rB, lb + 24576 + h * 4096);
        }
    };

    auto compute = [&](int cur) {
        bf16x8 a_h[4], a_l[4], b_h[4], b_l[4];
#pragma unroll
        for (int mi = 0; mi < 4; ++mi) {
            a_h[mi] = *(const bf16x8*)&lds[cur][0][wm + mi * 16 + l15][quad * 8];
            a_l[mi] = *(const bf16x8*)&lds[cur][1][wm + mi * 16 + l15][quad * 8];
        }
#pragma unroll
        for (int ni = 0; ni < 4; ++ni) {
            b_h[ni] = *(const bf16x8*)&lds[cur][2][wn + ni * 16 + l15][quad * 8];
            b_l[ni] = *(const bf16x8*)&lds[cur][3][wn + ni * 16 + l15][quad * 8];
        }
#pragma unroll
        for (int mi = 0; mi < 4; ++mi)
#pragma unroll
            for (int ni = 0; ni < 4; ++ni) {
                acc[mi][ni] = __builtin_amdgcn_mfma_f32_16x16x32_bf16(a_h[mi], b_h[ni], acc[mi][ni], 0, 0, 0);
                acc[mi][ni] = __builtin_amdgcn_mfma_f32_16x16x32_bf16(a_l[mi], b_h[ni], acc[mi][ni], 0, 0, 0);
                acc[mi][ni] = __builtin_amdgcn_mfma_f32_16x16x32_bf16(a_h[mi], b_l[ni], acc[mi][ni], 0, 0, 0);
            }
    };

    stage(0, 0);
    __syncthreads();               // drains stage-0 DMA (auto vmcnt(0))
    int cur = 0;
    for (int it = 0; it < 15; ++it) {
        stage(cur ^ 1, (it + 1) * 32);   // async into other buffer
        compute(cur);                     // 16 ds_read_b128 + 48 MFMA of cover
        __syncthreads();                  // drain next-buf DMA, publish
        cur ^= 1;
    }
    compute(cur);

    // epilogue: C/D layout col=lane&15, row=quad*4+reg (m89/m91-verified)
#pragma unroll
    for (int ni = 0; ni < 4; ++ni) {
        const int col = n0 + wn + ni * 16 + l15;
        const float bb = bias[col] * bscale;
#pragma unroll
        for (int mi = 0; mi < 4; ++mi) {
            const int row = m0 + wm + mi * 16 + quad * 4;
#pragma unroll
            for (int rr = 0; rr < 4; ++rr) {
                Y[(size_t)(row + rr) * D_SZ + col] = acc[mi][ni][rr] + bb;
            }
        }
    }
}

// ---------------------------------------------------------------------------
// Kernel 2: per batch b, f(s) = sum_j exp2(s*kL_j)*v_j / sum_j exp2(s*kL_j);
// out[b,i] = f(q_i). Phase 1: f on a 64-pt uniform grid over [qmin,qmax];
// 4 threads per grid point (each sweeps 128 j's, 2 shfl_xor combine).
// Phase 2: Lagrange-cubic interpolation at each q_i (2 i/thread).
// k/v LDS in 4x136-float segments: the wave's 4 distinct 16B read
// addresses land on distinct bank groups (conflict-free).
// ---------------------------------------------------------------------------
__global__ __launch_bounds__(256) void attn_kernel(
    const float* __restrict__ qkv, float* __restrict__ out)
{
    const int b = blockIdx.x;
    const int t = threadIdx.x;

    const float* __restrict__ q = qkv + (size_t)b * D_SZ;
    const float* __restrict__ k = qkv + (size_t)B_SZ * D_SZ + (size_t)b * D_SZ;   // already *log2e
    const float* __restrict__ v = qkv + (size_t)2 * B_SZ * D_SZ + (size_t)b * D_SZ;

    __shared__ __align__(16) float kk_s[4 * SEG];
    __shared__ __align__(16) float vv_s[4 * SEG];
    __shared__ __align__(16) float fgrid[NGRID];
    __shared__ float redmax[4], redmin[4];

    // ---- stage k,v to LDS (segmented), load this thread's q rows ----
    const int i0 = t, i1 = t + 256;
    const float q0 = q[i0];
    const float q1 = q[i1];
    {
        const int j   = 2 * t;
        const int pos = (j >> 7) * SEG + (j & 127);
        float2 kf = *(const float2*)&k[j];
        float2 vf = *(const float2*)&v[j];
        *(float2*)&kk_s[pos] = kf;
        *(float2*)&vv_s[pos] = vf;
    }

    // ---- q-range reduction (grid support) ----
    float qmax = fmaxf(q0, q1), qmin = fminf(q0, q1);
#pragma unroll
    for (int off = 32; off > 0; off >>= 1) {
        qmax = fmaxf(qmax, __shfl_xor(qmax, off));
        qmin = fminf(qmin, __shfl_xor(qmin, off));
    }
    const int wave = t >> 6;
    if ((t & 63) == 0) { redmax[wave] = qmax; redmin[wave] = qmin; }
    __syncthreads();   // also publishes kk_s/vv_s
    qmax = fmaxf(fmaxf(redmax[0], redmax[1]), fmaxf(redmax[2], redmax[3]));
    qmin = fminf(fminf(redmin[0], redmin[1]), fminf(redmin[2], redmin[3]));

    const float h    = fmaxf((qmax - qmin) * (1.0f / (float)(NGRID - 3)), 1e-30f);
    const float s0   = qmin - h;                 // grid: s_g = s0 + g*h
    const float invh = 1.0f / h;                 // q in [s_1, s_{NGRID-2}]

    // ---- phase 1: grid evaluation (4 threads per grid point) ----
    {
        const int   g   = t >> 2;
        const int   sub = t & 3;
        const int   jb  = sub * SEG;
        const float sg  = s0 + (float)g * h;
        const f32x2 sgg = {sg, sg};

        f32x2 dena = {0.f, 0.f}, denb = {0.f, 0.f};
        f32x2 numa = {0.f, 0.f}, numb = {0.f, 0.f};
#pragma unroll 4
        for (int jj = 0; jj < 128; jj += 4) {
            f32x4 kq = *(const f32x4*)&kk_s[jb + jj];
            f32x4 vq = *(const f32x4*)&vv_s[jb + jj];
            f32x2 ka = {kq.x, kq.y}, kb_ = {kq.z, kq.w};
            f32x2 va = {vq.x, vq.y}, vb_ = {vq.z, vq.w};

            f32x2 ea = pk_mul(sgg, ka);
            f32x2 eb = pk_mul(sgg, kb_);
            // in-place v_exp_f32 on the pair's own registers (no repack)
            ea.x = exp2_raw(ea.x); ea.y = exp2_raw(ea.y);
            eb.x = exp2_raw(eb.x); eb.y = exp2_raw(eb.y);

            dena = pk_add(dena, ea);
            denb = pk_add(denb, eb);
            numa = pk_fma(ea, va, numa);
            numb = pk_fma(eb, vb_, numb);
        }
        float den = (dena.x + dena.y) + (denb.x + denb.y);
        float num = (numa.x + numa.y) + (numb.x + numb.y);
        den += __shfl_xor(den, 1);  num += __shfl_xor(num, 1);
        den += __shfl_xor(den, 2);  num += __shfl_xor(num, 2);
        if (sub == 0) fgrid[g] = num / den;
    }
    __syncthreads();

    // ---- phase 2: cubic interpolation at q_i ----
#pragma unroll
    for (int r = 0; r < 2; ++r) {
        const float qi = (r == 0) ? q0 : q1;
        const int   ii = (r == 0) ? i0 : i1;

        float u  = (qi - s0) * invh;
        int   ic = (int)floorf(u);
        ic = (ic < 1) ? 1 : ((ic > NGRID - 3) ? (NGRID - 3) : ic);
        float uu = u - (float)ic;

        float f0 = fgrid[ic - 1];
        float f1 = fgrid[ic];
        float f2 = fgrid[ic + 1];
        float f3 = fgrid[ic + 2];

        const float um1 = uu - 1.0f, um2 = uu - 2.0f, up1 = uu + 1.0f;
        const float w0 = -uu * um1 * um2 * (1.0f / 6.0f);
        const float w1 =  up1 * um1 * um2 * 0.5f;
        const float w2 = -up1 * uu  * um2 * 0.5f;
        const float w3 =  up1 * uu  * um1 * (1.0f / 6.0f);

        out[(size_t)b * D_SZ + ii] = w0 * f0 + w1 * f1 + w2 * f2 + w3 * f3;
    }
}

extern "C" void kernel_launch(void* const* d_in, const int* in_sizes, int n_in,
                              void* d_out, int out_size, void* d_ws, size_t ws_size,
                              hipStream_t stream) {
    const float* query = (const float*)d_in[0];
    const float* key_  = (const float*)d_in[1];
    const float* value = (const float*)d_in[2];
    const float* Wq    = (const float*)d_in[3];
    const float* bq    = (const float*)d_in[4];
    const float* Wk    = (const float*)d_in[5];
    const float* bk    = (const float*)d_in[6];
    const float* Wv    = (const float*)d_in[7];
    const float* bv    = (const float*)d_in[8];
    float* out = (float*)d_out;

    // workspace layout (28.3 MB total):
    float* qkv = (float*)d_ws;                                  // 3*B*D f32 = 12.58 MB
    unsigned short* xhi = (unsigned short*)(qkv + (size_t)3 * B_SZ * D_SZ);  // 6.29 MB
    unsigned short* xlo = xhi + (size_t)3 * B_SZ * D_SZ;                     // 6.29 MB
    unsigned short* whi = xlo + (size_t)3 * B_SZ * D_SZ;                     // 1.57 MB
    unsigned short* wlo = whi + (size_t)3 * D_SZ * D_SZ;                     // 1.57 MB

    dim3 g0(512, 1, 6);   // X needs 512 blocks/z, W early-outs past 128
    split_prepass<<<g0, 256, 0, stream>>>(query, key_, value, Wq, Wk, Wv,
                                          xhi, xlo, whi, wlo);

    dim3 g1(B_SZ / 128, D_SZ / 128, 3);
    qkv_gemm_mfma<<<g1, 256, 0, stream>>>(xhi, xlo, whi, wlo, bq, bk, bv, qkv);

    attn_kernel<<<B_SZ, 256, 0, stream>>>(qkv, out);
}

// Round 5
// 108.968 us; speedup vs baseline: 1.4416x; 1.0197x over previous
//
#include <hip/hip_runtime.h>

// Problem: B=2048, D=512, all fp32.
// q = query@Wq.T+bq ; k,v likewise. attn[b,i,j]=q_i*k_j (rank-1!),
// softmax over j, out[b,i] = sum_j softmax_j(q_i*k_j)*v_j.
//
// Round 9 (single-variable: GEMM only; attn/prepass byte-identical to r8):
//  - GEMM: 64x64 tile, 768 blocks (3 blocks/CU -> cross-block overlap hides
//    the per-step DMA drain; r8's 128x128/192-block version had 1 block/CU
//    and nothing to overlap the 32KB drain with). Staging via
//    global_load_lds(16B), wave-specialized: wave w DMAs slab w
//    (Ahi/Alo/Bhi/Blo), 4 loads/lane, wave-uniform LDS base (lane*16
//    implicit). LDS [2][4][64][32] shorts = 32 KiB, double-buffered,
//    one __syncthreads per K-step. Per wave per step: 8 ds_read_b128 +
//    12 MFMA (3-term split-bf16 into 2x2 16x16x32 frags).
//
// Ledger (r4 post-mortem): the 256MiB workspace poison fill (~45us) is part
// of the timed graph every iteration -> optimizable budget is kernels+gaps.

#define B_SZ 2048
#define D_SZ 512
#define LOG2E 1.44269504088896340736f
#define NGRID 64
#define SEG 136   // 128 floats payload + 8 pad: segment s starts at bank 8s

typedef __attribute__((ext_vector_type(2))) float  f32x2;
typedef __attribute__((ext_vector_type(4))) float  f32x4;
typedef __attribute__((ext_vector_type(8))) short  bf16x8;   // MFMA A/B carrier
typedef __attribute__((ext_vector_type(4))) unsigned short u16x4;
typedef __attribute__((ext_vector_type(8))) unsigned short u16x8;

__device__ __forceinline__ float exp2_raw(float x) {
#if defined(__has_builtin) && __has_builtin(__builtin_amdgcn_exp2f)
    return __builtin_amdgcn_exp2f(x);
#else
    return exp2f(x);
#endif
}

// Forced packed fp32 math (compiler emits scalar for f32x2 exprs otherwise).
__device__ __forceinline__ f32x2 pk_fma(f32x2 a, f32x2 b, f32x2 c) {
    f32x2 d;
    asm("v_pk_fma_f32 %0, %1, %2, %3" : "=v"(d) : "v"(a), "v"(b), "v"(c));
    return d;
}
__device__ __forceinline__ f32x2 pk_add(f32x2 a, f32x2 b) {
    f32x2 d;
    asm("v_pk_add_f32 %0, %1, %2" : "=v"(d) : "v"(a), "v"(b));
    return d;
}
__device__ __forceinline__ f32x2 pk_mul(f32x2 a, f32x2 b) {
    f32x2 d;
    asm("v_pk_mul_f32 %0, %1, %2" : "=v"(d) : "v"(a), "v"(b));
    return d;
}

// async global->LDS, 16B per lane. lds ptr must be wave-uniform (HW adds
// lane*16). Guide: m97/m193 pattern, size must be a literal.
__device__ __forceinline__ void gload16(const void* g, void* l) {
    __builtin_amdgcn_global_load_lds(
        (const __attribute__((address_space(1))) unsigned int*)g,
        (__attribute__((address_space(3))) unsigned int*)l,
        16, 0, 0);
}

// Truncation split: hi = top 16 bits of fp32; lo = bf16(trunc) of residual.
// |x - hi - lo| <= 2^-14 |x|
__device__ __forceinline__ void split1(float x, unsigned short& hi, unsigned short& lo) {
    unsigned int u = __float_as_uint(x);
    hi = (unsigned short)(u >> 16);
    float r = x - __uint_as_float(u & 0xFFFF0000u);
    lo = (unsigned short)(__float_as_uint(r) >> 16);
}

__device__ __forceinline__ void split4(const float4& x, u16x4& h, u16x4& l) {
    unsigned short hh, ll;
    split1(x.x, hh, ll); h.x = hh; l.x = ll;
    split1(x.y, hh, ll); h.y = hh; l.y = ll;
    split1(x.z, hh, ll); h.z = hh; l.z = ll;
    split1(x.w, hh, ll); h.w = hh; l.w = ll;
}

// ---------------------------------------------------------------------------
// Kernel 0: one-time hi/lo split of X (query,key,value) and W (Wq,Wk,Wv).
// z = 0..2 -> X inputs (2048x512), z = 3..5 -> W (512x512). z==4 (Wk) is
// pre-scaled by log2(e) so the GEMM emits k already in log2 domain.
// ---------------------------------------------------------------------------
__global__ __launch_bounds__(256) void split_prepass(
    const float* __restrict__ Xq, const float* __restrict__ Xk, const float* __restrict__ Xv,
    const float* __restrict__ Wq, const float* __restrict__ Wk, const float* __restrict__ Wv,
    unsigned short* __restrict__ xhi, unsigned short* __restrict__ xlo,
    unsigned short* __restrict__ whi, unsigned short* __restrict__ wlo)
{
    const int z = blockIdx.z;
    const bool isW = (z >= 3);
    if (isW && blockIdx.x >= 128) return;   // W needs only 128 blocks

    const float* __restrict__ src =
        (z == 0) ? Xq : (z == 1) ? Xk : (z == 2) ? Xv :
        (z == 3) ? Wq : (z == 4) ? Wk : Wv;
    unsigned short* dh;
    unsigned short* dl;
    if (!isW) { size_t o = (size_t)z * B_SZ * D_SZ;       dh = xhi + o; dl = xlo + o; }
    else      { size_t o = (size_t)(z - 3) * D_SZ * D_SZ; dh = whi + o; dl = wlo + o; }

    const size_t i = ((size_t)blockIdx.x * 256 + threadIdx.x) * 8;
    const float s = (z == 4) ? LOG2E : 1.0f;

    float4 a = *(const float4*)(src + i);
    float4 b = *(const float4*)(src + i + 4);
    a.x *= s; a.y *= s; a.z *= s; a.w *= s;
    b.x *= s; b.y *= s; b.z *= s; b.w *= s;

    u16x4 h0, l0, h1, l1;
    split4(a, h0, l0);
    split4(b, h1, l1);
    u16x8 hh = {h0.x, h0.y, h0.z, h0.w, h1.x, h1.y, h1.z, h1.w};
    u16x8 ll = {l0.x, l0.y, l0.z, l0.w, l1.x, l1.y, l1.z, l1.w};
    *(u16x8*)(dh + i) = hh;
    *(u16x8*)(dl + i) = ll;
}

// ---------------------------------------------------------------------------
// Kernel 1: Y = X @ W^T + bias via split-bf16 MFMA.
// 64x64 tile, 256 thr = 4 waves (2x2, 32x32 each -> 2x2 frags of 16x16x32).
// BK=32, LDS [2 buf][4 slab][64][32] shorts = 32 KiB (5 blocks/CU cap; grid
// gives 3). Staging: wave w DMAs slab w via 4x global_load_lds(16B)/lane;
// LDS dest wave-uniform + h*1024 (lane*16 implicit -> linear, rule-safe).
// One __syncthreads per K-step; 8 ds_read_b128 + 12 MFMA per wave of cover,
// plus 2 other resident blocks to overlap the DMA drain.
// ---------------------------------------------------------------------------
__global__ __launch_bounds__(256) void qkv_gemm_mfma(
    const unsigned short* __restrict__ xhi, const unsigned short* __restrict__ xlo,
    const unsigned short* __restrict__ whi, const unsigned short* __restrict__ wlo,
    const float* __restrict__ bq, const float* __restrict__ bk, const float* __restrict__ bv,
    float* __restrict__ qkv_out)
{
    const int which = blockIdx.z;
    const unsigned short* __restrict__ Ah = xhi + (size_t)which * B_SZ * D_SZ;
    const unsigned short* __restrict__ Al = xlo + (size_t)which * B_SZ * D_SZ;
    const unsigned short* __restrict__ Bh = whi + (size_t)which * D_SZ * D_SZ;
    const unsigned short* __restrict__ Bl = wlo + (size_t)which * D_SZ * D_SZ;
    const float* __restrict__ bias = (which == 0) ? bq : (which == 1) ? bk : bv;
    const float bscale = (which == 1) ? LOG2E : 1.0f;   // k: W pre-scaled, bias too
    float* __restrict__ Y = qkv_out + (size_t)which * B_SZ * D_SZ;

    const int t    = threadIdx.x;
    const int lane = t & 63;
    const int wv   = t >> 6;
    const int l15  = lane & 15;
    const int quad = lane >> 4;
    const int wm   = (wv >> 1) * 32;
    const int wn   = (wv & 1) * 32;
    const int m0   = blockIdx.x * 64;
    const int n0   = blockIdx.y * 64;

    // [buf][slab][row][k] ; slab: 0=Ahi 1=Alo 2=Bhi 3=Blo ; 32768 B total
    __shared__ unsigned short lds[2][4][64][32];

    f32x4 acc[2][2] = {};

    // wave-specialized staging: wave wv owns slab wv
    const unsigned short* __restrict__ gbase =
        (wv == 0) ? Ah : (wv == 1) ? Al : (wv == 2) ? Bh : Bl;
    const int tile0 = (wv < 2) ? m0 : n0;
    const size_t goff = (size_t)(tile0 + (lane >> 2)) * D_SZ + (lane & 3) * 8;

    auto stage = [&](int cur, int kk) {
        char* lb = (char*)&lds[cur][wv][0][0];          // wave-uniform
        const unsigned short* g = gbase + goff + kk;
#pragma unroll
        for (int h = 0; h < 4; ++h) {
            gload16(g + (size_t)h * 16 * D_SZ, lb + h * 1024);
        }
    };

    auto compute = [&](int cur) {
        bf16x8 a_h[2], a_l[2], b_h[2], b_l[2];
#pragma unroll
        for (int mi = 0; mi < 2; ++mi) {
            a_h[mi] = *(const bf16x8*)&lds[cur][0][wm + mi * 16 + l15][quad * 8];
            a_l[mi] = *(const bf16x8*)&lds[cur][1][wm + mi * 16 + l15][quad * 8];
        }
#pragma unroll
        for (int ni = 0; ni < 2; ++ni) {
            b_h[ni] = *(const bf16x8*)&lds[cur][2][wn + ni * 16 + l15][quad * 8];
            b_l[ni] = *(const bf16x8*)&lds[cur][3][wn + ni * 16 + l15][quad * 8];
        }
#pragma unroll
        for (int mi = 0; mi < 2; ++mi)
#pragma unroll
            for (int ni = 0; ni < 2; ++ni) {
                acc[mi][ni] = __builtin_amdgcn_mfma_f32_16x16x32_bf16(a_h[mi], b_h[ni], acc[mi][ni], 0, 0, 0);
                acc[mi][ni] = __builtin_amdgcn_mfma_f32_16x16x32_bf16(a_l[mi], b_h[ni], acc[mi][ni], 0, 0, 0);
                acc[mi][ni] = __builtin_amdgcn_mfma_f32_16x16x32_bf16(a_h[mi], b_l[ni], acc[mi][ni], 0, 0, 0);
            }
    };

    stage(0, 0);
    __syncthreads();               // drains stage-0 DMA (auto vmcnt(0))
    int cur = 0;
    for (int it = 0; it < 15; ++it) {
        stage(cur ^ 1, (it + 1) * 32);   // async into other buffer
        compute(cur);                     // 8 ds_read_b128 + 12 MFMA of cover
        __syncthreads();                  // drain next-buf DMA, publish
        cur ^= 1;
    }
    compute(cur);

    // epilogue: C/D layout col=lane&15, row=quad*4+reg (m89/m91-verified)
#pragma unroll
    for (int ni = 0; ni < 2; ++ni) {
        const int col = n0 + wn + ni * 16 + l15;
        const float bb = bias[col] * bscale;
#pragma unroll
        for (int mi = 0; mi < 2; ++mi) {
            const int row = m0 + wm + mi * 16 + quad * 4;
#pragma unroll
            for (int rr = 0; rr < 4; ++rr) {
                Y[(size_t)(row + rr) * D_SZ + col] = acc[mi][ni][rr] + bb;
            }
        }
    }
}

// ---------------------------------------------------------------------------
// Kernel 2: per batch b, f(s) = sum_j exp2(s*kL_j)*v_j / sum_j exp2(s*kL_j);
// out[b,i] = f(q_i). Phase 1: f on a 64-pt uniform grid over [qmin,qmax];
// 4 threads per grid point (each sweeps 128 j's, 2 shfl_xor combine).
// Phase 2: Lagrange-cubic interpolation at each q_i (2 i/thread).
// (Byte-identical to round 8 -- control variable this round.)
// ---------------------------------------------------------------------------
__global__ __launch_bounds__(256) void attn_kernel(
    const float* __restrict__ qkv, float* __restrict__ out)
{
    const int b = blockIdx.x;
    const int t = threadIdx.x;

    const float* __restrict__ q = qkv + (size_t)b * D_SZ;
    const float* __restrict__ k = qkv + (size_t)B_SZ * D_SZ + (size_t)b * D_SZ;   // already *log2e
    const float* __restrict__ v = qkv + (size_t)2 * B_SZ * D_SZ + (size_t)b * D_SZ;

    __shared__ __align__(16) float kk_s[4 * SEG];
    __shared__ __align__(16) float vv_s[4 * SEG];
    __shared__ __align__(16) float fgrid[NGRID];
    __shared__ float redmax[4], redmin[4];

    // ---- stage k,v to LDS (segmented), load this thread's q rows ----
    const int i0 = t, i1 = t + 256;
    const float q0 = q[i0];
    const float q1 = q[i1];
    {
        const int j   = 2 * t;
        const int pos = (j >> 7) * SEG + (j & 127);
        float2 kf = *(const float2*)&k[j];
        float2 vf = *(const float2*)&v[j];
        *(float2*)&kk_s[pos] = kf;
        *(float2*)&vv_s[pos] = vf;
    }

    // ---- q-range reduction (grid support) ----
    float qmax = fmaxf(q0, q1), qmin = fminf(q0, q1);
#pragma unroll
    for (int off = 32; off > 0; off >>= 1) {
        qmax = fmaxf(qmax, __shfl_xor(qmax, off));
        qmin = fminf(qmin, __shfl_xor(qmin, off));
    }
    const int wave = t >> 6;
    if ((t & 63) == 0) { redmax[wave] = qmax; redmin[wave] = qmin; }
    __syncthreads();   // also publishes kk_s/vv_s
    qmax = fmaxf(fmaxf(redmax[0], redmax[1]), fmaxf(redmax[2], redmax[3]));
    qmin = fminf(fminf(redmin[0], redmin[1]), fminf(redmin[2], redmin[3]));

    const float h    = fmaxf((qmax - qmin) * (1.0f / (float)(NGRID - 3)), 1e-30f);
    const float s0   = qmin - h;                 // grid: s_g = s0 + g*h
    const float invh = 1.0f / h;                 // q in [s_1, s_{NGRID-2}]

    // ---- phase 1: grid evaluation (4 threads per grid point) ----
    {
        const int   g   = t >> 2;
        const int   sub = t & 3;
        const int   jb  = sub * SEG;
        const float sg  = s0 + (float)g * h;
        const f32x2 sgg = {sg, sg};

        f32x2 dena = {0.f, 0.f}, denb = {0.f, 0.f};
        f32x2 numa = {0.f, 0.f}, numb = {0.f, 0.f};
#pragma unroll 4
        for (int jj = 0; jj < 128; jj += 4) {
            f32x4 kq = *(const f32x4*)&kk_s[jb + jj];
            f32x4 vq = *(const f32x4*)&vv_s[jb + jj];
            f32x2 ka = {kq.x, kq.y}, kb_ = {kq.z, kq.w};
            f32x2 va = {vq.x, vq.y}, vb_ = {vq.z, vq.w};

            f32x2 ea = pk_mul(sgg, ka);
            f32x2 eb = pk_mul(sgg, kb_);
            // in-place v_exp_f32 on the pair's own registers (no repack)
            ea.x = exp2_raw(ea.x); ea.y = exp2_raw(ea.y);
            eb.x = exp2_raw(eb.x); eb.y = exp2_raw(eb.y);

            dena = pk_add(dena, ea);
            denb = pk_add(denb, eb);
            numa = pk_fma(ea, va, numa);
            numb = pk_fma(eb, vb_, numb);
        }
        float den = (dena.x + dena.y) + (denb.x + denb.y);
        float num = (numa.x + numa.y) + (numb.x + numb.y);
        den += __shfl_xor(den, 1);  num += __shfl_xor(num, 1);
        den += __shfl_xor(den, 2);  num += __shfl_xor(num, 2);
        if (sub == 0) fgrid[g] = num / den;
    }
    __syncthreads();

    // ---- phase 2: cubic interpolation at q_i ----
#pragma unroll
    for (int r = 0; r < 2; ++r) {
        const float qi = (r == 0) ? q0 : q1;
        const int   ii = (r == 0) ? i0 : i1;

        float u  = (qi - s0) * invh;
        int   ic = (int)floorf(u);
        ic = (ic < 1) ? 1 : ((ic > NGRID - 3) ? (NGRID - 3) : ic);
        float uu = u - (float)ic;

        float f0 = fgrid[ic - 1];
        float f1 = fgrid[ic];
        float f2 = fgrid[ic + 1];
        float f3 = fgrid[ic + 2];

        const float um1 = uu - 1.0f, um2 = uu - 2.0f, up1 = uu + 1.0f;
        const float w0 = -uu * um1 * um2 * (1.0f / 6.0f);
        const float w1 =  up1 * um1 * um2 * 0.5f;
        const float w2 = -up1 * uu  * um2 * 0.5f;
        const float w3 =  up1 * uu  * um1 * (1.0f / 6.0f);

        out[(size_t)b * D_SZ + ii] = w0 * f0 + w1 * f1 + w2 * f2 + w3 * f3;
    }
}

extern "C" void kernel_launch(void* const* d_in, const int* in_sizes, int n_in,
                              void* d_out, int out_size, void* d_ws, size_t ws_size,
                              hipStream_t stream) {
    const float* query = (const float*)d_in[0];
    const float* key_  = (const float*)d_in[1];
    const float* value = (const float*)d_in[2];
    const float* Wq    = (const float*)d_in[3];
    const float* bq    = (const float*)d_in[4];
    const float* Wk    = (const float*)d_in[5];
    const float* bk    = (const float*)d_in[6];
    const float* Wv    = (const float*)d_in[7];
    const float* bv    = (const float*)d_in[8];
    float* out = (float*)d_out;

    // workspace layout (28.3 MB total):
    float* qkv = (float*)d_ws;                                  // 3*B*D f32 = 12.58 MB
    unsigned short* xhi = (unsigned short*)(qkv + (size_t)3 * B_SZ * D_SZ);  // 6.29 MB
    unsigned short* xlo = xhi + (size_t)3 * B_SZ * D_SZ;                     // 6.29 MB
    unsigned short* whi = xlo + (size_t)3 * B_SZ * D_SZ;                     // 1.57 MB
    unsigned short* wlo = whi + (size_t)3 * D_SZ * D_SZ;                     // 1.57 MB

    dim3 g0(512, 1, 6);   // X needs 512 blocks/z, W early-outs past 128
    split_prepass<<<g0, 256, 0, stream>>>(query, key_, value, Wq, Wk, Wv,
                                          xhi, xlo, whi, wlo);

    dim3 g1(B_SZ / 64, D_SZ / 64, 3);
    qkv_gemm_mfma<<<g1, 256, 0, stream>>>(xhi, xlo, whi, wlo, bq, bk, bv, qkv);

    attn_kernel<<<B_SZ, 256, 0, stream>>>(qkv, out);
}

// Round 6
// 105.161 us; speedup vs baseline: 1.4938x; 1.0362x over previous
//
#include <hip/hip_runtime.h>

// Problem: B=2048, D=512, all fp32.
// q = query@Wq.T+bq ; k,v likewise. attn[b,i,j]=q_i*k_j (rank-1!),
// softmax over j, out[b,i] = sum_j softmax_j(q_i*k_j)*v_j.
//
// Round 10: collapse to 2 kernels.
//  - split_prepass DELETED. GEMM stages fp32 X/W directly via
//    global_load_lds (same DMA bytes as hi/lo: 4 B/elem) and splits to
//    hi/lo bf16 in registers after the ds_read (hidden under the DMA
//    drain -- r0<->r1 showed split-VALU is free there). fp32 rows are
//    128 B, so frag reads use the both-sides-or-neither XOR swizzle:
//    stage fetches global granule g^(row&7) into linear LDS slot g
//    (per-lane global addr), read XORs the same -> uniform 2 lanes/slot.
//  - k's log2e scale moves to attn's LDS staging (r2 arrangement).
//  - attn otherwise byte-identical to r9; gemm geometry unchanged
//    (64x64 tile, BK=32, wave-specialized DMA, 768 blocks = 3/CU).
//
// Ledger: ~44us workspace poison fill is a fixed timed cost every iter;
// optimizable budget is kernels + launch gaps.

#define B_SZ 2048
#define D_SZ 512
#define LOG2E 1.44269504088896340736f
#define NGRID 64
#define SEG 136   // 128 floats payload + 8 pad: segment s starts at bank 8s

typedef __attribute__((ext_vector_type(2))) float  f32x2;
typedef __attribute__((ext_vector_type(4))) float  f32x4;
typedef __attribute__((ext_vector_type(8))) short  bf16x8;   // MFMA A/B carrier

__device__ __forceinline__ float exp2_raw(float x) {
#if defined(__has_builtin) && __has_builtin(__builtin_amdgcn_exp2f)
    return __builtin_amdgcn_exp2f(x);
#else
    return exp2f(x);
#endif
}

// Forced packed fp32 math (compiler emits scalar for f32x2 exprs otherwise).
__device__ __forceinline__ f32x2 pk_fma(f32x2 a, f32x2 b, f32x2 c) {
    f32x2 d;
    asm("v_pk_fma_f32 %0, %1, %2, %3" : "=v"(d) : "v"(a), "v"(b), "v"(c));
    return d;
}
__device__ __forceinline__ f32x2 pk_add(f32x2 a, f32x2 b) {
    f32x2 d;
    asm("v_pk_add_f32 %0, %1, %2" : "=v"(d) : "v"(a), "v"(b));
    return d;
}
__device__ __forceinline__ f32x2 pk_mul(f32x2 a, f32x2 b) {
    f32x2 d;
    asm("v_pk_mul_f32 %0, %1, %2" : "=v"(d) : "v"(a), "v"(b));
    return d;
}

// async global->LDS, 16B per lane. lds ptr must be wave-uniform (HW adds
// lane*16); the GLOBAL address is per-lane (enables source pre-swizzle).
__device__ __forceinline__ void gload16(const void* g, void* l) {
    __builtin_amdgcn_global_load_lds(
        (const __attribute__((address_space(1))) unsigned int*)g,
        (__attribute__((address_space(3))) unsigned int*)l,
        16, 0, 0);
}

// Truncation split: hi = top 16 bits of fp32; lo = bf16(trunc) of residual.
// |x - hi - lo| <= 2^-14 |x|
__device__ __forceinline__ void split1(float x, unsigned short& hi, unsigned short& lo) {
    unsigned int u = __float_as_uint(x);
    hi = (unsigned short)(u >> 16);
    float r = x - __uint_as_float(u & 0xFFFF0000u);
    lo = (unsigned short)(__float_as_uint(r) >> 16);
}

// 8 fp32 (two f32x4, k ascending) -> hi/lo bf16x8 fragments
__device__ __forceinline__ void split8(const f32x4 p0, const f32x4 p1,
                                       bf16x8& h, bf16x8& l) {
    unsigned short hh, ll;
    split1(p0.x, hh, ll); h[0] = (short)hh; l[0] = (short)ll;
    split1(p0.y, hh, ll); h[1] = (short)hh; l[1] = (short)ll;
    split1(p0.z, hh, ll); h[2] = (short)hh; l[2] = (short)ll;
    split1(p0.w, hh, ll); h[3] = (short)hh; l[3] = (short)ll;
    split1(p1.x, hh, ll); h[4] = (short)hh; l[4] = (short)ll;
    split1(p1.y, hh, ll); h[5] = (short)hh; l[5] = (short)ll;
    split1(p1.z, hh, ll); h[6] = (short)hh; l[6] = (short)ll;
    split1(p1.w, hh, ll); h[7] = (short)hh; l[7] = (short)ll;
}

// ---------------------------------------------------------------------------
// Kernel 1: Y = X @ W^T + bias via split-bf16 MFMA, staging fp32 directly.
// 64x64 tile, 256 thr = 4 waves (2x2, 32x32 each -> 2x2 frags of 16x16x32).
// BK=32, LDS [2 buf][2 op][64 row][32 k] fp32 = 32 KiB (3 blocks/CU).
// Staging: wave w stages op w>>1, row-half w&1: 4x gload16/lane, source
// granule XOR-swizzled (g^(row&7)); LDS dest linear. Frag reads apply the
// same XOR -> uniform bank use. Split to hi/lo bf16 in regs, 12 MFMA/step.
// ---------------------------------------------------------------------------
__global__ __launch_bounds__(256) void qkv_gemm_mfma(
    const float* __restrict__ Xq, const float* __restrict__ Xk, const float* __restrict__ Xv,
    const float* __restrict__ Wq, const float* __restrict__ Wk, const float* __restrict__ Wv,
    const float* __restrict__ bq, const float* __restrict__ bk, const float* __restrict__ bv,
    float* __restrict__ qkv_out)
{
    const int which = blockIdx.z;
    const float* __restrict__ X    = (which == 0) ? Xq : (which == 1) ? Xk : Xv;
    const float* __restrict__ W    = (which == 0) ? Wq : (which == 1) ? Wk : Wv;
    const float* __restrict__ bias = (which == 0) ? bq : (which == 1) ? bk : bv;
    float* __restrict__ Y = qkv_out + (size_t)which * B_SZ * D_SZ;

    const int t    = threadIdx.x;
    const int lane = t & 63;
    const int wv   = t >> 6;
    const int l15  = lane & 15;
    const int quad = lane >> 4;
    const int wm   = (wv >> 1) * 32;
    const int wn   = (wv & 1) * 32;
    const int m0   = blockIdx.x * 64;
    const int n0   = blockIdx.y * 64;

    // [buf][op][row][k] fp32 ; op: 0=A(X rows) 1=B(W rows) ; 32768 B
    __shared__ float lds[2][2][64][32];

    f32x4 acc[2][2] = {};

    // wave-specialized staging: op = wv>>1, row half = wv&1
    const int   op    = wv >> 1;
    const int   wsub  = wv & 1;
    const float* __restrict__ gsrc = (op == 0) ? X : W;
    const int   tile0 = (op == 0) ? m0 : n0;
    // lane covers (row = wsub*32 + h*8 + lane/8, granule g = lane&7);
    // source granule pre-swizzled: g ^ (row&7) = (lane&7) ^ ((lane>>3)&7)
    const int grow   = tile0 + wsub * 32 + (lane >> 3);
    const int gcolsw = ((lane & 7) ^ ((lane >> 3) & 7)) * 4;
    const float* gl0 = gsrc + (size_t)grow * D_SZ + gcolsw;

    auto stage = [&](int cur, int kk) {
        char* lb = (char*)&lds[cur][op][wsub * 32][0];    // wave-uniform
        const float* g = gl0 + kk;
#pragma unroll
        for (int h = 0; h < 4; ++h) {
            gload16(g + (size_t)(h * 8) * D_SZ, lb + h * 1024);
        }
    };

    auto compute = [&](int cur) {
        bf16x8 a_h[2], a_l[2], b_h[2], b_l[2];
        const int sw = l15 & 7;                 // row&7 for frag rows
        const int g0 = (quad << 1) ^ sw;        // swizzled granule of k=quad*8
        const int g1 = ((quad << 1) | 1) ^ sw;  // swizzled granule of k=quad*8+4
#pragma unroll
        for (int mi = 0; mi < 2; ++mi) {
            const float* rp = &lds[cur][0][wm + mi * 16 + l15][0];
            f32x4 p0 = *(const f32x4*)(rp + (g0 << 2));
            f32x4 p1 = *(const f32x4*)(rp + (g1 << 2));
            split8(p0, p1, a_h[mi], a_l[mi]);
        }
#pragma unroll
        for (int ni = 0; ni < 2; ++ni) {
            const float* rp = &lds[cur][1][wn + ni * 16 + l15][0];
            f32x4 p0 = *(const f32x4*)(rp + (g0 << 2));
            f32x4 p1 = *(const f32x4*)(rp + (g1 << 2));
            split8(p0, p1, b_h[ni], b_l[ni]);
        }
#pragma unroll
        for (int mi = 0; mi < 2; ++mi)
#pragma unroll
            for (int ni = 0; ni < 2; ++ni) {
                acc[mi][ni] = __builtin_amdgcn_mfma_f32_16x16x32_bf16(a_h[mi], b_h[ni], acc[mi][ni], 0, 0, 0);
                acc[mi][ni] = __builtin_amdgcn_mfma_f32_16x16x32_bf16(a_l[mi], b_h[ni], acc[mi][ni], 0, 0, 0);
                acc[mi][ni] = __builtin_amdgcn_mfma_f32_16x16x32_bf16(a_h[mi], b_l[ni], acc[mi][ni], 0, 0, 0);
            }
    };

    stage(0, 0);
    __syncthreads();               // drains stage-0 DMA (auto vmcnt(0))
    int cur = 0;
    for (int it = 0; it < 15; ++it) {
        stage(cur ^ 1, (it + 1) * 32);   // async into other buffer
        compute(cur);                     // ds_reads + split + 12 MFMA cover
        __syncthreads();                  // drain next-buf DMA, publish
        cur ^= 1;
    }
    compute(cur);

    // epilogue: C/D layout col=lane&15, row=quad*4+reg (m89/m91-verified)
#pragma unroll
    for (int ni = 0; ni < 2; ++ni) {
        const int col = n0 + wn + ni * 16 + l15;
        const float bb = bias[col];
#pragma unroll
        for (int mi = 0; mi < 2; ++mi) {
            const int row = m0 + wm + mi * 16 + quad * 4;
#pragma unroll
            for (int rr = 0; rr < 4; ++rr) {
                Y[(size_t)(row + rr) * D_SZ + col] = acc[mi][ni][rr] + bb;
            }
        }
    }
}

// ---------------------------------------------------------------------------
// Kernel 2: per batch b, f(s) = sum_j exp2(s*kL_j)*v_j / sum_j exp2(s*kL_j);
// out[b,i] = f(q_i). kL = k*log2e applied at LDS staging (k from gemm is
// plain now). Phase 1: f on a 64-pt uniform grid over [qmin,qmax]; 4
// threads per grid point (each sweeps 128 j's, 2 shfl_xor combine).
// Phase 2: Lagrange-cubic interpolation at each q_i (2 i/thread).
// ---------------------------------------------------------------------------
__global__ __launch_bounds__(256) void attn_kernel(
    const float* __restrict__ qkv, float* __restrict__ out)
{
    const int b = blockIdx.x;
    const int t = threadIdx.x;

    const float* __restrict__ q = qkv + (size_t)b * D_SZ;
    const float* __restrict__ k = qkv + (size_t)B_SZ * D_SZ + (size_t)b * D_SZ;
    const float* __restrict__ v = qkv + (size_t)2 * B_SZ * D_SZ + (size_t)b * D_SZ;

    __shared__ __align__(16) float kk_s[4 * SEG];
    __shared__ __align__(16) float vv_s[4 * SEG];
    __shared__ __align__(16) float fgrid[NGRID];
    __shared__ float redmax[4], redmin[4];

    // ---- stage k*log2e, v to LDS (segmented), load this thread's q rows ----
    const int i0 = t, i1 = t + 256;
    const float q0 = q[i0];
    const float q1 = q[i1];
    {
        const int j   = 2 * t;
        const int pos = (j >> 7) * SEG + (j & 127);
        float2 kf = *(const float2*)&k[j];
        float2 vf = *(const float2*)&v[j];
        kf.x *= LOG2E;
        kf.y *= LOG2E;
        *(float2*)&kk_s[pos] = kf;
        *(float2*)&vv_s[pos] = vf;
    }

    // ---- q-range reduction (grid support) ----
    float qmax = fmaxf(q0, q1), qmin = fminf(q0, q1);
#pragma unroll
    for (int off = 32; off > 0; off >>= 1) {
        qmax = fmaxf(qmax, __shfl_xor(qmax, off));
        qmin = fminf(qmin, __shfl_xor(qmin, off));
    }
    const int wave = t >> 6;
    if ((t & 63) == 0) { redmax[wave] = qmax; redmin[wave] = qmin; }
    __syncthreads();   // also publishes kk_s/vv_s
    qmax = fmaxf(fmaxf(redmax[0], redmax[1]), fmaxf(redmax[2], redmax[3]));
    qmin = fminf(fminf(redmin[0], redmin[1]), fminf(redmin[2], redmin[3]));

    const float h    = fmaxf((qmax - qmin) * (1.0f / (float)(NGRID - 3)), 1e-30f);
    const float s0   = qmin - h;                 // grid: s_g = s0 + g*h
    const float invh = 1.0f / h;                 // q in [s_1, s_{NGRID-2}]

    // ---- phase 1: grid evaluation (4 threads per grid point) ----
    {
        const int   g   = t >> 2;
        const int   sub = t & 3;
        const int   jb  = sub * SEG;
        const float sg  = s0 + (float)g * h;
        const f32x2 sgg = {sg, sg};

        f32x2 dena = {0.f, 0.f}, denb = {0.f, 0.f};
        f32x2 numa = {0.f, 0.f}, numb = {0.f, 0.f};
#pragma unroll 4
        for (int jj = 0; jj < 128; jj += 4) {
            f32x4 kq = *(const f32x4*)&kk_s[jb + jj];
            f32x4 vq = *(const f32x4*)&vv_s[jb + jj];
            f32x2 ka = {kq.x, kq.y}, kb_ = {kq.z, kq.w};
            f32x2 va = {vq.x, vq.y}, vb_ = {vq.z, vq.w};

            f32x2 ea = pk_mul(sgg, ka);
            f32x2 eb = pk_mul(sgg, kb_);
            // in-place v_exp_f32 on the pair's own registers (no repack)
            ea.x = exp2_raw(ea.x); ea.y = exp2_raw(ea.y);
            eb.x = exp2_raw(eb.x); eb.y = exp2_raw(eb.y);

            dena = pk_add(dena, ea);
            denb = pk_add(denb, eb);
            numa = pk_fma(ea, va, numa);
            numb = pk_fma(eb, vb_, numb);
        }
        float den = (dena.x + dena.y) + (denb.x + denb.y);
        float num = (numa.x + numa.y) + (numb.x + numb.y);
        den += __shfl_xor(den, 1);  num += __shfl_xor(num, 1);
        den += __shfl_xor(den, 2);  num += __shfl_xor(num, 2);
        if (sub == 0) fgrid[g] = num / den;
    }
    __syncthreads();

    // ---- phase 2: cubic interpolation at q_i ----
#pragma unroll
    for (int r = 0; r < 2; ++r) {
        const float qi = (r == 0) ? q0 : q1;
        const int   ii = (r == 0) ? i0 : i1;

        float u  = (qi - s0) * invh;
        int   ic = (int)floorf(u);
        ic = (ic < 1) ? 1 : ((ic > NGRID - 3) ? (NGRID - 3) : ic);
        float uu = u - (float)ic;

        float f0 = fgrid[ic - 1];
        float f1 = fgrid[ic];
        float f2 = fgrid[ic + 1];
        float f3 = fgrid[ic + 2];

        const float um1 = uu - 1.0f, um2 = uu - 2.0f, up1 = uu + 1.0f;
        const float w0 = -uu * um1 * um2 * (1.0f / 6.0f);
        const float w1 =  up1 * um1 * um2 * 0.5f;
        const float w2 = -up1 * uu  * um2 * 0.5f;
        const float w3 =  up1 * uu  * um1 * (1.0f / 6.0f);

        out[(size_t)b * D_SZ + ii] = w0 * f0 + w1 * f1 + w2 * f2 + w3 * f3;
    }
}

extern "C" void kernel_launch(void* const* d_in, const int* in_sizes, int n_in,
                              void* d_out, int out_size, void* d_ws, size_t ws_size,
                              hipStream_t stream) {
    const float* query = (const float*)d_in[0];
    const float* key_  = (const float*)d_in[1];
    const float* value = (const float*)d_in[2];
    const float* Wq    = (const float*)d_in[3];
    const float* bq    = (const float*)d_in[4];
    const float* Wk    = (const float*)d_in[5];
    const float* bk    = (const float*)d_in[6];
    const float* Wv    = (const float*)d_in[7];
    const float* bv    = (const float*)d_in[8];
    float* out = (float*)d_out;

    // workspace: qkv fp32 [3][B][D] = 12.58 MB
    float* qkv = (float*)d_ws;

    dim3 g1(B_SZ / 64, D_SZ / 64, 3);
    qkv_gemm_mfma<<<g1, 256, 0, stream>>>(query, key_, value, Wq, Wk, Wv,
                                          bq, bk, bv, qkv);

    attn_kernel<<<B_SZ, 256, 0, stream>>>(qkv, out);
}